// Round 2
// baseline (1579.126 us; speedup 1.0000x reference)
//
#include <hip/hip_runtime.h>

#define N_NODES 100000
#define N_EDGES 1600000
#define N_GRAPHS 512
#define X_DIM 4
#define H 64
#define LAYERS 3
#define NUM_CLASS 3
#define NPB 32  // nodes per block in lin_kernel

// h[n][f] = sum_k x[n][k] * Wemb[k][f] + bemb[f]
__global__ void embed_kernel(const float* __restrict__ x, const float* __restrict__ Wemb,
                             const float* __restrict__ bemb, float* __restrict__ h) {
    int i = blockIdx.x * blockDim.x + threadIdx.x;
    if (i >= N_NODES * H) return;
    int n = i >> 6, f = i & 63;
    float acc = bemb[f];
#pragma unroll
    for (int k = 0; k < X_DIM; ++k)
        acc += x[n * X_DIM + k] * Wemb[k * H + f];
    h[i] = acc;
}

// a = h@W1 + b1 ; b = h@W2 ; agg = h@W3 + b3   (f32)
__global__ __launch_bounds__(256) void lin_kernel(
    const float* __restrict__ h,
    const float* __restrict__ W1, const float* __restrict__ bias1,
    const float* __restrict__ W2,
    const float* __restrict__ W3, const float* __restrict__ bias3,
    float* __restrict__ a, float* __restrict__ b, float* __restrict__ agg) {
    __shared__ float ws1[H * H], ws2[H * H], ws3[H * H], hs[NPB * H];
    int t = threadIdx.x;
    for (int i = t; i < H * H; i += 256) {
        ws1[i] = W1[i];
        ws2[i] = W2[i];
        ws3[i] = W3[i];
    }
    int nbase = blockIdx.x * NPB;
    for (int i = t; i < NPB * H; i += 256) {
        int n = nbase + (i >> 6);
        hs[i] = (n < N_NODES) ? h[(size_t)n * H + (i & 63)] : 0.0f;
    }
    __syncthreads();
    int f = t & 63, g = t >> 6;  // g in 0..3; this thread handles nodes g*8 .. g*8+7
    float acc1[8], acc2[8], acc3[8];
#pragma unroll
    for (int i = 0; i < 8; ++i) { acc1[i] = 0.f; acc2[i] = 0.f; acc3[i] = 0.f; }
    for (int k = 0; k < H; ++k) {
        float w1 = ws1[k * H + f], w2 = ws2[k * H + f], w3 = ws3[k * H + f];
#pragma unroll
        for (int i = 0; i < 8; ++i) {
            float hk = hs[(g * 8 + i) * H + k];  // wave-uniform -> LDS broadcast
            acc1[i] += hk * w1;
            acc2[i] += hk * w2;
            acc3[i] += hk * w3;
        }
    }
    float bb1 = bias1[f], bb3 = bias3[f];
#pragma unroll
    for (int i = 0; i < 8; ++i) {
        int n = nbase + g * 8 + i;
        if (n < N_NODES) {
            size_t o = (size_t)n * H + f;
            a[o] = acc1[i] + bb1;
            b[o] = acc2[i];
            agg[o] = acc3[i] + bb3;
        }
    }
}

// agg[d] += (a[s] - b[d]) * ea[e]   (64 lanes = 64 features per edge)
__global__ void edge_kernel(const int* __restrict__ src, const int* __restrict__ dst,
                            const float* __restrict__ ea,
                            const float* __restrict__ a, const float* __restrict__ b,
                            float* __restrict__ agg) {
    long long idx = (long long)blockIdx.x * blockDim.x + threadIdx.x;
    int e = (int)(idx >> 6), f = (int)(idx & 63);
    if (e >= N_EDGES) return;
    int s = src[e], d = dst[e];
    if ((unsigned)s >= N_NODES || (unsigned)d >= N_NODES) return;  // insurance
    float w = ea[e];
    float msg = (a[(size_t)s * H + f] - b[(size_t)d * H + f]) * w;
    atomicAdd(&agg[(size_t)d * H + f], msg);
}

__global__ void relu_kernel(const float* __restrict__ agg, float* __restrict__ h) {
    int i = blockIdx.x * blockDim.x + threadIdx.x;
    if (i < N_NODES * H) h[i] = fmaxf(agg[i], 0.0f);
}

__global__ void pool_kernel(const float* __restrict__ h, const int* __restrict__ batch,
                            float* __restrict__ pool, float* __restrict__ cnt) {
    int i = blockIdx.x * blockDim.x + threadIdx.x;
    if (i >= N_NODES * H) return;
    int n = i >> 6, f = i & 63;
    int g = batch[n];
    if ((unsigned)g >= N_GRAPHS) return;
    atomicAdd(&pool[g * H + f], h[i]);
    if (f == 0) atomicAdd(&cnt[g], 1.0f);
}

// per graph: gx = pool/cnt; hid = relu(gx@Wf1+bf1); out = hid@Wf2+bf2
__global__ void head_kernel(const float* __restrict__ pool, const float* __restrict__ cnt,
                            const float* __restrict__ Wf1, const float* __restrict__ bf1v,
                            const float* __restrict__ Wf2, const float* __restrict__ bf2v,
                            float* __restrict__ out) {
    __shared__ float gx[H], hid[2 * H];
    int g = blockIdx.x, t = threadIdx.x;
    if (t < H) gx[t] = pool[g * H + t] / fmaxf(cnt[g], 1.0f);
    __syncthreads();
    float acc = bf1v[t];
    for (int k = 0; k < H; ++k) acc += gx[k] * Wf1[k * 2 * H + t];
    hid[t] = fmaxf(acc, 0.0f);
    __syncthreads();
    if (t < NUM_CLASS) {
        float o = bf2v[t];
        for (int k = 0; k < 2 * H; ++k) o += hid[k] * Wf2[k * NUM_CLASS + t];
        out[g * NUM_CLASS + t] = o;
    }
}

extern "C" void kernel_launch(void* const* d_in, const int* in_sizes, int n_in,
                              void* d_out, int out_size, void* d_ws, size_t ws_size,
                              hipStream_t stream) {
    const float* x    = (const float*)d_in[0];
    const int*  ei    = (const int*)d_in[1];
    const int*  batch = (const int*)d_in[2];
    const float* ea   = (const float*)d_in[3];
    const float* Wemb = (const float*)d_in[4];
    const float* bemb = (const float*)d_in[5];
    const float* pW1  = (const float*)d_in[6];
    const float* pb1  = (const float*)d_in[7];
    const float* pW2  = (const float*)d_in[8];
    const float* pW3  = (const float*)d_in[9];
    const float* pb3  = (const float*)d_in[10];
    const float* Wf1  = (const float*)d_in[11];
    const float* bf1v = (const float*)d_in[12];
    const float* Wf2  = (const float*)d_in[13];
    const float* bf2v = (const float*)d_in[14];
    float* out = (float*)d_out;

    float* ws = (float*)d_ws;
    const size_t NH = (size_t)N_NODES * H;
    float* h    = ws;
    float* a    = ws + NH;
    float* b    = ws + 2 * NH;
    float* agg  = ws + 3 * NH;
    float* pool = ws + 4 * NH;
    float* cnt  = pool + (size_t)N_GRAPHS * H;

    const int* src = ei;
    const int* dst = ei + N_EDGES;

    embed_kernel<<<(N_NODES * H + 255) / 256, 256, 0, stream>>>(x, Wemb, bemb, h);

    for (int l = 0; l < LAYERS; ++l) {
        lin_kernel<<<(N_NODES + NPB - 1) / NPB, 256, 0, stream>>>(
            h, pW1 + (size_t)l * H * H, pb1 + (size_t)l * H,
            pW2 + (size_t)l * H * H,
            pW3 + (size_t)l * H * H, pb3 + (size_t)l * H,
            a, b, agg);
        edge_kernel<<<(int)(((long long)N_EDGES * H + 255) / 256), 256, 0, stream>>>(
            src, dst, ea, a, b, agg);
        relu_kernel<<<(N_NODES * H + 255) / 256, 256, 0, stream>>>(agg, h);
    }

    hipMemsetAsync(pool, 0, ((size_t)N_GRAPHS * H + N_GRAPHS) * sizeof(float), stream);
    pool_kernel<<<(N_NODES * H + 255) / 256, 256, 0, stream>>>(h, batch, pool, cnt);
    head_kernel<<<N_GRAPHS, 2 * H, 0, stream>>>(pool, cnt, Wf1, bf1v, Wf2, bf2v, out);
}

// Round 4
// 854.319 us; speedup vs baseline: 1.8484x; 1.8484x over previous
//
#include <hip/hip_runtime.h>

#define N_NODES 100000
#define N_EDGES 1600000
#define N_GRAPHS 512
#define X_DIM 4
#define H 64
#define LAYERS 3
#define NUM_CLASS 3
#define NPB 32      // nodes per block in lin_kernel
#define CHUNK 512   // scan chunk
#define NCHUNK ((N_NODES + CHUNK - 1) / CHUNK)  // 196

// ---------------- embed: h = x @ Wemb + bemb ----------------
__global__ void embed_kernel(const float* __restrict__ x, const float* __restrict__ Wemb,
                             const float* __restrict__ bemb, float* __restrict__ h) {
    int i = blockIdx.x * blockDim.x + threadIdx.x;
    if (i >= N_NODES * H) return;
    int n = i >> 6, f = i & 63;
    float acc = bemb[f];
#pragma unroll
    for (int k = 0; k < X_DIM; ++k)
        acc += x[n * X_DIM + k] * Wemb[k * H + f];
    h[i] = acc;
}

// ---------------- CSR build ----------------
// deg[d]++, degw[d]+=ea  per edge
__global__ void count_kernel(const int* __restrict__ dst, const float* __restrict__ ea,
                             int* __restrict__ deg, float* __restrict__ degw) {
    int e = blockIdx.x * blockDim.x + threadIdx.x;
    if (e >= N_EDGES) return;
    int d = dst[e];
    if ((unsigned)d >= N_NODES) return;
    atomicAdd(deg + d, 1);
    atomicAdd(degw + d, ea[e]);
}

// per-chunk inclusive scan of deg -> row_ptr[i+1] (pre-offset), chunk totals -> partials
__global__ __launch_bounds__(CHUNK) void scan1_kernel(const int* __restrict__ deg,
                                                      int* __restrict__ row_ptr,
                                                      int* __restrict__ partials) {
    __shared__ int s[CHUNK];
    int tid = threadIdx.x;
    int i = blockIdx.x * CHUNK + tid;
    int v = (i < N_NODES) ? deg[i] : 0;
    s[tid] = v;
    for (int off = 1; off < CHUNK; off <<= 1) {
        __syncthreads();
        int t = (tid >= off) ? s[tid - off] : 0;
        __syncthreads();
        s[tid] += t;
    }
    __syncthreads();
    if (i < N_NODES) row_ptr[i + 1] = s[tid];
    if (tid == CHUNK - 1) partials[blockIdx.x] = s[tid];
}

// exclusive scan of partials (NCHUNK <= 256) -> chunk_off
__global__ __launch_bounds__(256) void scan2_kernel(const int* __restrict__ partials,
                                                    int* __restrict__ chunk_off) {
    __shared__ int s[256];
    int tid = threadIdx.x;
    s[tid] = (tid < NCHUNK) ? partials[tid] : 0;
    for (int off = 1; off < 256; off <<= 1) {
        __syncthreads();
        int t = (tid >= off) ? s[tid - off] : 0;
        __syncthreads();
        s[tid] += t;
    }
    __syncthreads();
    int excl = (tid == 0) ? 0 : s[tid - 1];
    __syncthreads();
    if (tid < NCHUNK) chunk_off[tid] = excl;
}

// add chunk offsets; init fill cursor; row_ptr[0]=0
__global__ void scan3_kernel(const int* __restrict__ deg, const int* __restrict__ chunk_off,
                             int* __restrict__ row_ptr, int* __restrict__ cur) {
    int i = blockIdx.x * blockDim.x + threadIdx.x;
    if (i >= N_NODES) return;
    int v = row_ptr[i + 1] + chunk_off[i / CHUNK];
    row_ptr[i + 1] = v;
    cur[i] = v - deg[i];  // row start
    if (i == 0) row_ptr[0] = 0;
}

// scatter (src, ea) pairs into CSR order
__global__ void fill_kernel(const int* __restrict__ src, const int* __restrict__ dst,
                            const float* __restrict__ ea,
                            int* __restrict__ cur, int2* __restrict__ epack) {
    int e = blockIdx.x * blockDim.x + threadIdx.x;
    if (e >= N_EDGES) return;
    int d = dst[e];
    if ((unsigned)d >= N_NODES) return;
    int pos = atomicAdd(cur + d, 1);
    epack[pos] = make_int2(src[e], __float_as_int(ea[e]));
}

// ---------------- lin: a = h@W1+b1 ; agg_init = h@W3+b3 - (h@W2)*degw ----------------
__global__ __launch_bounds__(256) void lin_kernel(
    const float* __restrict__ h, const float* __restrict__ degw,
    const float* __restrict__ W1, const float* __restrict__ bias1,
    const float* __restrict__ W2,
    const float* __restrict__ W3, const float* __restrict__ bias3,
    float* __restrict__ a, float* __restrict__ agg) {
    __shared__ float ws1[H * H], ws2[H * H], ws3[H * H], hs[NPB * H];
    int t = threadIdx.x;
    for (int i = t; i < H * H; i += 256) {
        ws1[i] = W1[i];
        ws2[i] = W2[i];
        ws3[i] = W3[i];
    }
    int nbase = blockIdx.x * NPB;
    for (int i = t; i < NPB * H; i += 256) {
        int n = nbase + (i >> 6);
        hs[i] = (n < N_NODES) ? h[(size_t)n * H + (i & 63)] : 0.0f;
    }
    __syncthreads();
    int f = t & 63, g = t >> 6;  // this thread: feature f for nodes g*8 .. g*8+7
    float acc1[8], acc2[8], acc3[8];
#pragma unroll
    for (int i = 0; i < 8; ++i) { acc1[i] = 0.f; acc2[i] = 0.f; acc3[i] = 0.f; }
    for (int k0 = 0; k0 < H; k0 += 8) {
        float w1r[8], w2r[8], w3r[8];
#pragma unroll
        for (int kk = 0; kk < 8; ++kk) {
            w1r[kk] = ws1[(k0 + kk) * H + f];
            w2r[kk] = ws2[(k0 + kk) * H + f];
            w3r[kk] = ws3[(k0 + kk) * H + f];
        }
#pragma unroll
        for (int i = 0; i < 8; ++i) {
#pragma unroll
            for (int kk = 0; kk < 8; ++kk) {
                float hk = hs[(g * 8 + i) * H + k0 + kk];
                acc1[i] += hk * w1r[kk];
                acc2[i] += hk * w2r[kk];
                acc3[i] += hk * w3r[kk];
            }
        }
    }
    float bb1 = bias1[f], bb3 = bias3[f];
#pragma unroll
    for (int i = 0; i < 8; ++i) {
        int n = nbase + g * 8 + i;
        if (n < N_NODES) {
            size_t o = (size_t)n * H + f;
            float dw = degw[n];
            a[o] = acc1[i] + bb1;
            agg[o] = acc3[i] + bb3 - acc2[i] * dw;
        }
    }
}

// ---------------- gather: h[d] = relu(agg_init[d] + sum_in ea*a[src]) ----------------
__global__ __launch_bounds__(256) void gather_kernel(
    const int* __restrict__ row_ptr, const int2* __restrict__ epack,
    const float* __restrict__ a, const float* __restrict__ agg_init,
    float* __restrict__ h) {
    int n = blockIdx.x * 4 + (threadIdx.x >> 6);
    if (n >= N_NODES) return;
    int f = threadIdx.x & 63;
    int beg = row_ptr[n], end = row_ptr[n + 1];
    float acc = agg_init[(size_t)n * H + f];
    int j = beg;
    for (; j + 3 < end; j += 4) {
        int2 p0 = epack[j], p1 = epack[j + 1], p2 = epack[j + 2], p3 = epack[j + 3];
        float a0 = a[(size_t)p0.x * H + f];
        float a1 = a[(size_t)p1.x * H + f];
        float a2 = a[(size_t)p2.x * H + f];
        float a3 = a[(size_t)p3.x * H + f];
        acc += __int_as_float(p0.y) * a0;
        acc += __int_as_float(p1.y) * a1;
        acc += __int_as_float(p2.y) * a2;
        acc += __int_as_float(p3.y) * a3;
    }
    for (; j < end; ++j) {
        int2 p = epack[j];
        acc += __int_as_float(p.y) * a[(size_t)p.x * H + f];
    }
    h[(size_t)n * H + f] = fmaxf(acc, 0.0f);
}

// ---------------- fused mean-pool + MLP head (batch is sorted) ----------------
__device__ __forceinline__ int lower_bound(const int* __restrict__ arr, int n, int key) {
    int lo = 0, hi = n;
    while (lo < hi) {
        int mid = (lo + hi) >> 1;
        if (arr[mid] < key) lo = mid + 1; else hi = mid;
    }
    return lo;
}

__global__ __launch_bounds__(128) void poolhead_kernel(
    const float* __restrict__ h, const int* __restrict__ batch,
    const float* __restrict__ Wf1, const float* __restrict__ bf1v,
    const float* __restrict__ Wf2, const float* __restrict__ bf2v,
    float* __restrict__ out) {
    __shared__ float psum[128];
    __shared__ float gx[H];
    __shared__ float hid[2 * H];
    int g = blockIdx.x, t = threadIdx.x;
    int s = lower_bound(batch, N_NODES, g);
    int e = lower_bound(batch, N_NODES, g + 1);
    int w = t >> 6, f = t & 63;
    float accf = 0.0f;
    for (int n = s + w; n < e; n += 2) accf += h[(size_t)n * H + f];
    psum[t] = accf;
    __syncthreads();
    if (t < H) {
        float c = (float)(e - s);
        gx[t] = (psum[t] + psum[t + 64]) / fmaxf(c, 1.0f);
    }
    __syncthreads();
    float acc = bf1v[t];
    for (int k = 0; k < H; ++k) acc += gx[k] * Wf1[k * 2 * H + t];
    hid[t] = fmaxf(acc, 0.0f);
    __syncthreads();
    if (t < NUM_CLASS) {
        float o = bf2v[t];
        for (int k = 0; k < 2 * H; ++k) o += hid[k] * Wf2[k * NUM_CLASS + t];
        out[g * NUM_CLASS + t] = o;
    }
}

extern "C" void kernel_launch(void* const* d_in, const int* in_sizes, int n_in,
                              void* d_out, int out_size, void* d_ws, size_t ws_size,
                              hipStream_t stream) {
    const float* x    = (const float*)d_in[0];
    const int*  ei    = (const int*)d_in[1];
    const int*  batch = (const int*)d_in[2];
    const float* ea   = (const float*)d_in[3];
    const float* Wemb = (const float*)d_in[4];
    const float* bemb = (const float*)d_in[5];
    const float* pW1  = (const float*)d_in[6];
    const float* pb1  = (const float*)d_in[7];
    const float* pW2  = (const float*)d_in[8];
    const float* pW3  = (const float*)d_in[9];
    const float* pb3  = (const float*)d_in[10];
    const float* Wf1  = (const float*)d_in[11];
    const float* bf1v = (const float*)d_in[12];
    const float* Wf2  = (const float*)d_in[13];
    const float* bf2v = (const float*)d_in[14];
    float* out = (float*)d_out;

    const int* src = ei;
    const int* dst = ei + N_EDGES;

    // ---- workspace layout ----
    char* wsb = (char*)d_ws;
    const size_t NH = (size_t)N_NODES * H;
    float* h        = (float*)wsb;                      // NH floats
    float* a        = h + NH;                           // NH floats
    float* agg      = a + NH;                           // NH floats
    int2*  epack    = (int2*)(agg + NH);                // N_EDGES int2 (8B aligned)
    int*   deg      = (int*)(epack + N_EDGES);          // N_NODES
    int*   row_ptr  = deg + N_NODES;                    // N_NODES+1
    int*   cur      = row_ptr + N_NODES + 1;            // N_NODES
    float* degw     = (float*)(cur + N_NODES);          // N_NODES
    int*   partials = (int*)(degw + N_NODES);           // NCHUNK
    int*   chunk_off= partials + NCHUNK;                // NCHUNK

    // ---- CSR build (once; ea/deg layer-independent) ----
    hipMemsetAsync(deg, 0, N_NODES * sizeof(int), stream);
    hipMemsetAsync(degw, 0, N_NODES * sizeof(float), stream);
    count_kernel<<<(N_EDGES + 255) / 256, 256, 0, stream>>>(dst, ea, deg, degw);
    scan1_kernel<<<NCHUNK, CHUNK, 0, stream>>>(deg, row_ptr, partials);
    scan2_kernel<<<1, 256, 0, stream>>>(partials, chunk_off);
    scan3_kernel<<<(N_NODES + 255) / 256, 256, 0, stream>>>(deg, chunk_off, row_ptr, cur);
    fill_kernel<<<(N_EDGES + 255) / 256, 256, 0, stream>>>(src, dst, ea, cur, epack);

    embed_kernel<<<(N_NODES * H + 255) / 256, 256, 0, stream>>>(x, Wemb, bemb, h);

    for (int l = 0; l < LAYERS; ++l) {
        lin_kernel<<<(N_NODES + NPB - 1) / NPB, 256, 0, stream>>>(
            h, degw,
            pW1 + (size_t)l * H * H, pb1 + (size_t)l * H,
            pW2 + (size_t)l * H * H,
            pW3 + (size_t)l * H * H, pb3 + (size_t)l * H,
            a, agg);
        gather_kernel<<<(N_NODES + 3) / 4, 256, 0, stream>>>(row_ptr, epack, a, agg, h);
    }

    poolhead_kernel<<<N_GRAPHS, 2 * H, 0, stream>>>(h, batch, Wf1, bf1v, Wf2, bf2v, out);
}

// Round 5
// 642.101 us; speedup vs baseline: 2.4593x; 1.3305x over previous
//
#include <hip/hip_runtime.h>

#define N_NODES 100000
#define N_EDGES 1600000
#define N_GRAPHS 512
#define X_DIM 4
#define H 64
#define LAYERS 3
#define NUM_CLASS 3
#define NPB 32              // nodes per block in lin_kernel
#define NBLK 256            // partition blocks
#define EPB (N_EDGES / NBLK)  // 6250 edges per partition block
#define BKT_BITS 9
#define BKT_SZ 512          // nodes per bucket
#define NBKT ((N_NODES + BKT_SZ - 1) / BKT_SZ)  // 196
#define MHIST (NBKT * NBLK)  // 50176, divisible by 512

// ---------------- embed: h = x @ Wemb + bemb ----------------
__global__ void embed_kernel(const float* __restrict__ x, const float* __restrict__ Wemb,
                             const float* __restrict__ bemb, float* __restrict__ h) {
    int i = blockIdx.x * blockDim.x + threadIdx.x;
    if (i >= N_NODES * H) return;
    int n = i >> 6, f = i & 63;
    float acc = bemb[f];
#pragma unroll
    for (int k = 0; k < X_DIM; ++k)
        acc += x[n * X_DIM + k] * Wemb[k * H + f];
    h[i] = acc;
}

// ---------------- phase A: per-block bucket histogram (LDS atomics only) ----------------
__global__ __launch_bounds__(256) void hist1_kernel(const int* __restrict__ dst,
                                                    int* __restrict__ histM) {
    __shared__ int hist[NBKT];
    int t = threadIdx.x, b = blockIdx.x;
    for (int i = t; i < NBKT; i += 256) hist[i] = 0;
    __syncthreads();
    int e0 = b * EPB;
    for (int j = t; j < EPB; j += 256) {
        int d = dst[e0 + j];
        atomicAdd(hist + (d >> BKT_BITS), 1);
    }
    __syncthreads();
    for (int i = t; i < NBKT; i += 256) histM[i * NBLK + b] = hist[i];
}

// ---------------- generic scan over MHIST entries ----------------
__global__ __launch_bounds__(512) void gscan1_kernel(const int* __restrict__ v,
                                                     int* __restrict__ incl,
                                                     int* __restrict__ partials) {
    __shared__ int s[512];
    int tid = threadIdx.x;
    int i = blockIdx.x * 512 + tid;
    int x = (i < MHIST) ? v[i] : 0;
    s[tid] = x;
    for (int off = 1; off < 512; off <<= 1) {
        __syncthreads();
        int tv = (tid >= off) ? s[tid - off] : 0;
        __syncthreads();
        s[tid] += tv;
    }
    __syncthreads();
    if (i < MHIST) incl[i] = s[tid];
    if (tid == 511) partials[blockIdx.x] = s[tid];
}

__global__ __launch_bounds__(512) void gscan2_kernel(const int* __restrict__ partials,
                                                     int* __restrict__ chunk_off, int nchunk) {
    __shared__ int s[512];
    int tid = threadIdx.x;
    s[tid] = (tid < nchunk) ? partials[tid] : 0;
    for (int off = 1; off < 512; off <<= 1) {
        __syncthreads();
        int tv = (tid >= off) ? s[tid - off] : 0;
        __syncthreads();
        s[tid] += tv;
    }
    __syncthreads();
    int excl = (tid == 0) ? 0 : s[tid - 1];
    __syncthreads();
    if (tid < nchunk) chunk_off[tid] = excl;
}

// ebase[i] = global exclusive prefix; bkt_ptr from bucket-major layout
__global__ void gscan3_kernel(const int* __restrict__ v, const int* __restrict__ incl,
                              const int* __restrict__ chunk_off,
                              int* __restrict__ ebase, int* __restrict__ bkt_ptr) {
    int i = blockIdx.x * 256 + threadIdx.x;
    if (i >= MHIST) return;
    int e = incl[i] + chunk_off[i >> 9] - v[i];
    ebase[i] = e;
    if ((i & (NBLK - 1)) == 0) bkt_ptr[i / NBLK] = e;
    if (i == MHIST - 1) bkt_ptr[NBKT] = e + v[i];
}

// ---------------- phase B: partition edges into bucket order (LDS cursors) ----------------
__global__ __launch_bounds__(256) void scatter1_kernel(
    const int* __restrict__ src, const int* __restrict__ dst, const float* __restrict__ ea,
    const int* __restrict__ ebase, int2* __restrict__ eb_sea, int* __restrict__ eb_dst) {
    __shared__ int cur[NBKT];
    int t = threadIdx.x, b = blockIdx.x;
    for (int i = t; i < NBKT; i += 256) cur[i] = ebase[i * NBLK + b];
    __syncthreads();
    int e0 = b * EPB;
    for (int j = t; j < EPB; j += 256) {
        int e = e0 + j;
        int d = dst[e];
        int k = d >> BKT_BITS;
        int pos = atomicAdd(cur + k, 1);
        eb_sea[pos] = make_int2(src[e], __float_as_int(ea[e]));
        eb_dst[pos] = d;
    }
}

// ---------------- phase C: per-bucket CSR build + degw (LDS atomics only) ----------------
__global__ __launch_bounds__(512) void bucket_kernel(
    const int* __restrict__ bkt_ptr, const int2* __restrict__ eb_sea,
    const int* __restrict__ eb_dst,
    int* __restrict__ row_ptr, float* __restrict__ degw, int2* __restrict__ epack) {
    __shared__ int cnt[BKT_SZ];
    __shared__ float dws[BKT_SZ];
    __shared__ int s[BKT_SZ];
    __shared__ int cur[BKT_SZ];
    int k = blockIdx.x, t = threadIdx.x;
    int base = k << BKT_BITS;
    int nn = N_NODES - base;
    if (nn > BKT_SZ) nn = BKT_SZ;
    cnt[t] = 0;
    dws[t] = 0.0f;
    __syncthreads();
    int beg = bkt_ptr[k], end = bkt_ptr[k + 1];
    for (int j = beg + t; j < end; j += 512) {
        int d = eb_dst[j] - base;
        atomicAdd(cnt + d, 1);
        atomicAdd(dws + d, __int_as_float(eb_sea[j].y));
    }
    __syncthreads();
    s[t] = cnt[t];
    for (int off = 1; off < 512; off <<= 1) {
        __syncthreads();
        int tv = (t >= off) ? s[t - off] : 0;
        __syncthreads();
        s[t] += tv;
    }
    __syncthreads();
    int rstart = beg + s[t] - cnt[t];  // exclusive within bucket + bucket base
    if (t < nn) {
        row_ptr[base + t] = rstart;
        degw[base + t] = dws[t];
        cur[t] = rstart;
    }
    __syncthreads();
    for (int j = beg + t; j < end; j += 512) {
        int2 se = eb_sea[j];
        int d = eb_dst[j] - base;
        int pos = atomicAdd(cur + d, 1);
        epack[pos] = se;
    }
    if (k == NBKT - 1 && t == 0) row_ptr[N_NODES] = N_EDGES;
}

// ---------------- lin: a = h@W1+b1 ; agg_init = h@W3+b3 - (h@W2)*degw ----------------
__global__ __launch_bounds__(256) void lin_kernel(
    const float* __restrict__ h, const float* __restrict__ degw,
    const float* __restrict__ W1, const float* __restrict__ bias1,
    const float* __restrict__ W2,
    const float* __restrict__ W3, const float* __restrict__ bias3,
    float* __restrict__ a, float* __restrict__ agg) {
    __shared__ float ws1[H * H], ws2[H * H], ws3[H * H], hs[NPB * H];
    int t = threadIdx.x;
    for (int i = t; i < H * H; i += 256) {
        ws1[i] = W1[i];
        ws2[i] = W2[i];
        ws3[i] = W3[i];
    }
    int nbase = blockIdx.x * NPB;
    for (int i = t; i < NPB * H; i += 256) {
        int n = nbase + (i >> 6);
        hs[i] = (n < N_NODES) ? h[(size_t)n * H + (i & 63)] : 0.0f;
    }
    __syncthreads();
    int f = t & 63, g = t >> 6;
    float acc1[8], acc2[8], acc3[8];
#pragma unroll
    for (int i = 0; i < 8; ++i) { acc1[i] = 0.f; acc2[i] = 0.f; acc3[i] = 0.f; }
    for (int k0 = 0; k0 < H; k0 += 8) {
        float w1r[8], w2r[8], w3r[8];
#pragma unroll
        for (int kk = 0; kk < 8; ++kk) {
            w1r[kk] = ws1[(k0 + kk) * H + f];
            w2r[kk] = ws2[(k0 + kk) * H + f];
            w3r[kk] = ws3[(k0 + kk) * H + f];
        }
#pragma unroll
        for (int i = 0; i < 8; ++i) {
#pragma unroll
            for (int kk = 0; kk < 8; ++kk) {
                float hk = hs[(g * 8 + i) * H + k0 + kk];
                acc1[i] += hk * w1r[kk];
                acc2[i] += hk * w2r[kk];
                acc3[i] += hk * w3r[kk];
            }
        }
    }
    float bb1 = bias1[f], bb3 = bias3[f];
#pragma unroll
    for (int i = 0; i < 8; ++i) {
        int n = nbase + g * 8 + i;
        if (n < N_NODES) {
            size_t o = (size_t)n * H + f;
            float dw = degw[n];
            a[o] = acc1[i] + bb1;
            agg[o] = acc3[i] + bb3 - acc2[i] * dw;
        }
    }
}

// ---------------- gather: h[d] = relu(agg_init[d] + sum_in ea*a[src]) ----------------
__global__ __launch_bounds__(256) void gather_kernel(
    const int* __restrict__ row_ptr, const int2* __restrict__ epack,
    const float* __restrict__ a, const float* __restrict__ agg_init,
    float* __restrict__ h) {
    int n = blockIdx.x * 4 + (threadIdx.x >> 6);
    if (n >= N_NODES) return;
    int f = threadIdx.x & 63;
    int beg = row_ptr[n], end = row_ptr[n + 1];
    float acc = agg_init[(size_t)n * H + f];
    int j = beg;
    for (; j + 3 < end; j += 4) {
        int2 p0 = epack[j], p1 = epack[j + 1], p2 = epack[j + 2], p3 = epack[j + 3];
        float a0 = a[(size_t)p0.x * H + f];
        float a1 = a[(size_t)p1.x * H + f];
        float a2 = a[(size_t)p2.x * H + f];
        float a3 = a[(size_t)p3.x * H + f];
        acc += __int_as_float(p0.y) * a0;
        acc += __int_as_float(p1.y) * a1;
        acc += __int_as_float(p2.y) * a2;
        acc += __int_as_float(p3.y) * a3;
    }
    for (; j < end; ++j) {
        int2 p = epack[j];
        acc += __int_as_float(p.y) * a[(size_t)p.x * H + f];
    }
    h[(size_t)n * H + f] = fmaxf(acc, 0.0f);
}

// ---------------- fused mean-pool + MLP head (batch is sorted) ----------------
__device__ __forceinline__ int lower_bound(const int* __restrict__ arr, int n, int key) {
    int lo = 0, hi = n;
    while (lo < hi) {
        int mid = (lo + hi) >> 1;
        if (arr[mid] < key) lo = mid + 1; else hi = mid;
    }
    return lo;
}

__global__ __launch_bounds__(128) void poolhead_kernel(
    const float* __restrict__ h, const int* __restrict__ batch,
    const float* __restrict__ Wf1, const float* __restrict__ bf1v,
    const float* __restrict__ Wf2, const float* __restrict__ bf2v,
    float* __restrict__ out) {
    __shared__ float psum[128];
    __shared__ float gx[H];
    __shared__ float hid[2 * H];
    int g = blockIdx.x, t = threadIdx.x;
    int s = lower_bound(batch, N_NODES, g);
    int e = lower_bound(batch, N_NODES, g + 1);
    int w = t >> 6, f = t & 63;
    float accf = 0.0f;
    for (int n = s + w; n < e; n += 2) accf += h[(size_t)n * H + f];
    psum[t] = accf;
    __syncthreads();
    if (t < H) {
        float c = (float)(e - s);
        gx[t] = (psum[t] + psum[t + 64]) / fmaxf(c, 1.0f);
    }
    __syncthreads();
    float acc = bf1v[t];
    for (int k = 0; k < H; ++k) acc += gx[k] * Wf1[k * 2 * H + t];
    hid[t] = fmaxf(acc, 0.0f);
    __syncthreads();
    if (t < NUM_CLASS) {
        float o = bf2v[t];
        for (int k = 0; k < 2 * H; ++k) o += hid[k] * Wf2[k * NUM_CLASS + t];
        out[g * NUM_CLASS + t] = o;
    }
}

extern "C" void kernel_launch(void* const* d_in, const int* in_sizes, int n_in,
                              void* d_out, int out_size, void* d_ws, size_t ws_size,
                              hipStream_t stream) {
    const float* x    = (const float*)d_in[0];
    const int*  ei    = (const int*)d_in[1];
    const int*  batch = (const int*)d_in[2];
    const float* ea   = (const float*)d_in[3];
    const float* Wemb = (const float*)d_in[4];
    const float* bemb = (const float*)d_in[5];
    const float* pW1  = (const float*)d_in[6];
    const float* pb1  = (const float*)d_in[7];
    const float* pW2  = (const float*)d_in[8];
    const float* pW3  = (const float*)d_in[9];
    const float* pb3  = (const float*)d_in[10];
    const float* Wf1  = (const float*)d_in[11];
    const float* bf1v = (const float*)d_in[12];
    const float* Wf2  = (const float*)d_in[13];
    const float* bf2v = (const float*)d_in[14];
    float* out = (float*)d_out;

    const int* src = ei;
    const int* dst = ei + N_EDGES;

    // ---- workspace layout ----
    const size_t NH = (size_t)N_NODES * H;
    float* h        = (float*)d_ws;                     // NH floats
    float* a        = h + NH;                           // NH floats
    float* agg      = a + NH;                           // NH floats
    int2*  epack    = (int2*)(agg + NH);                // N_EDGES int2
    int*   histM    = (int*)(epack + N_EDGES);          // MHIST
    int*   incl     = histM + MHIST;                    // MHIST
    int*   ebase    = incl + MHIST;                     // MHIST
    int*   partials = ebase + MHIST;                    // MHIST/512 = 98 (pad 512)
    int*   chunk_off= partials + 512;                   // 512
    int*   bkt_ptr  = chunk_off + 512;                  // NBKT+1
    int*   row_ptr  = bkt_ptr + NBKT + 1;               // N_NODES+1
    float* degw     = (float*)(row_ptr + N_NODES + 1);  // N_NODES
    // staging overlays a/agg (dead until lin_kernel; build completes first)
    int2*  eb_sea   = (int2*)a;                         // N_EDGES int2 (12.8 MB < 25.6)
    int*   eb_dst   = (int*)agg;                        // N_EDGES int  (6.4 MB < 25.6)

    // ---- CSR build: two-level LDS-atomic counting sort (no global atomics) ----
    hist1_kernel<<<NBLK, 256, 0, stream>>>(dst, histM);
    gscan1_kernel<<<MHIST / 512, 512, 0, stream>>>(histM, incl, partials);
    gscan2_kernel<<<1, 512, 0, stream>>>(partials, chunk_off, MHIST / 512);
    gscan3_kernel<<<(MHIST + 255) / 256, 256, 0, stream>>>(histM, incl, chunk_off, ebase, bkt_ptr);
    scatter1_kernel<<<NBLK, 256, 0, stream>>>(src, dst, ea, ebase, eb_sea, eb_dst);
    bucket_kernel<<<NBKT, 512, 0, stream>>>(bkt_ptr, eb_sea, eb_dst, row_ptr, degw, epack);

    embed_kernel<<<(N_NODES * H + 255) / 256, 256, 0, stream>>>(x, Wemb, bemb, h);

    for (int l = 0; l < LAYERS; ++l) {
        lin_kernel<<<(N_NODES + NPB - 1) / NPB, 256, 0, stream>>>(
            h, degw,
            pW1 + (size_t)l * H * H, pb1 + (size_t)l * H,
            pW2 + (size_t)l * H * H,
            pW3 + (size_t)l * H * H, pb3 + (size_t)l * H,
            a, agg);
        gather_kernel<<<(N_NODES + 3) / 4, 256, 0, stream>>>(row_ptr, epack, a, agg, h);
    }

    poolhead_kernel<<<N_GRAPHS, 2 * H, 0, stream>>>(h, batch, Wf1, bf1v, Wf2, bf2v, out);
}

// Round 6
// 585.820 us; speedup vs baseline: 2.6956x; 1.0961x over previous
//
#include <hip/hip_runtime.h>

#define N_NODES 100000
#define N_EDGES 1600000
#define N_GRAPHS 512
#define X_DIM 4
#define H 64
#define LAYERS 3
#define NUM_CLASS 3
#define NBLK 256            // partition blocks
#define EPB (N_EDGES / NBLK)  // 6250 edges per partition block
#define BKT_BITS 9
#define BKT_SZ 512          // nodes per bucket
#define NBKT ((N_NODES + BKT_SZ - 1) / BKT_SZ)  // 196
#define MHIST (NBKT * NBLK)  // 50176, divisible by 512
#define LROW 72             // padded LDS row (shorts): conflict-free + 16B aligned
#define NCHUNKS ((N_NODES + 63) / 64)  // 1563

typedef short bf16x8 __attribute__((ext_vector_type(8)));
typedef float floatx4 __attribute__((ext_vector_type(4)));

__device__ __forceinline__ unsigned short f2bf(float v) {
    unsigned u = __float_as_uint(v);
    unsigned r = (u + 0x7fff + ((u >> 16) & 1)) >> 16;  // round-nearest-even
    return (unsigned short)r;
}
__device__ __forceinline__ float bf2f(unsigned short s) {
    return __uint_as_float(((unsigned)s) << 16);
}

// ---------------- embed: h = x @ Wemb + bemb ----------------
__global__ void embed_kernel(const float* __restrict__ x, const float* __restrict__ Wemb,
                             const float* __restrict__ bemb, float* __restrict__ h) {
    int i = blockIdx.x * blockDim.x + threadIdx.x;
    if (i >= N_NODES * H) return;
    int n = i >> 6, f = i & 63;
    float acc = bemb[f];
#pragma unroll
    for (int k = 0; k < X_DIM; ++k)
        acc += x[n * X_DIM + k] * Wemb[k * H + f];
    h[i] = acc;
}

// ---------------- phase A: per-block bucket histogram (LDS atomics only) ----------------
__global__ __launch_bounds__(256) void hist1_kernel(const int* __restrict__ dst,
                                                    int* __restrict__ histM) {
    __shared__ int hist[NBKT];
    int t = threadIdx.x, b = blockIdx.x;
    for (int i = t; i < NBKT; i += 256) hist[i] = 0;
    __syncthreads();
    int e0 = b * EPB;
    for (int j = t; j < EPB; j += 256) {
        int d = dst[e0 + j];
        atomicAdd(hist + (d >> BKT_BITS), 1);
    }
    __syncthreads();
    for (int i = t; i < NBKT; i += 256) histM[i * NBLK + b] = hist[i];
}

// ---------------- generic scan over MHIST entries ----------------
__global__ __launch_bounds__(512) void gscan1_kernel(const int* __restrict__ v,
                                                     int* __restrict__ incl,
                                                     int* __restrict__ partials) {
    __shared__ int s[512];
    int tid = threadIdx.x;
    int i = blockIdx.x * 512 + tid;
    int x = (i < MHIST) ? v[i] : 0;
    s[tid] = x;
    for (int off = 1; off < 512; off <<= 1) {
        __syncthreads();
        int tv = (tid >= off) ? s[tid - off] : 0;
        __syncthreads();
        s[tid] += tv;
    }
    __syncthreads();
    if (i < MHIST) incl[i] = s[tid];
    if (tid == 511) partials[blockIdx.x] = s[tid];
}

__global__ __launch_bounds__(512) void gscan2_kernel(const int* __restrict__ partials,
                                                     int* __restrict__ chunk_off, int nchunk) {
    __shared__ int s[512];
    int tid = threadIdx.x;
    s[tid] = (tid < nchunk) ? partials[tid] : 0;
    for (int off = 1; off < 512; off <<= 1) {
        __syncthreads();
        int tv = (tid >= off) ? s[tid - off] : 0;
        __syncthreads();
        s[tid] += tv;
    }
    __syncthreads();
    int excl = (tid == 0) ? 0 : s[tid - 1];
    __syncthreads();
    if (tid < nchunk) chunk_off[tid] = excl;
}

// ebase[i] = global exclusive prefix; bkt_ptr from bucket-major layout
__global__ void gscan3_kernel(const int* __restrict__ v, const int* __restrict__ incl,
                              const int* __restrict__ chunk_off,
                              int* __restrict__ ebase, int* __restrict__ bkt_ptr) {
    int i = blockIdx.x * 256 + threadIdx.x;
    if (i >= MHIST) return;
    int e = incl[i] + chunk_off[i >> 9] - v[i];
    ebase[i] = e;
    if ((i & (NBLK - 1)) == 0) bkt_ptr[i / NBLK] = e;
    if (i == MHIST - 1) bkt_ptr[NBKT] = e + v[i];
}

// ---------------- phase B: partition edges into bucket order (LDS cursors) ----------------
__global__ __launch_bounds__(256) void scatter1_kernel(
    const int* __restrict__ src, const int* __restrict__ dst, const float* __restrict__ ea,
    const int* __restrict__ ebase, int2* __restrict__ eb_sea, int* __restrict__ eb_dst) {
    __shared__ int cur[NBKT];
    int t = threadIdx.x, b = blockIdx.x;
    for (int i = t; i < NBKT; i += 256) cur[i] = ebase[i * NBLK + b];
    __syncthreads();
    int e0 = b * EPB;
    for (int j = t; j < EPB; j += 256) {
        int e = e0 + j;
        int d = dst[e];
        int k = d >> BKT_BITS;
        int pos = atomicAdd(cur + k, 1);
        eb_sea[pos] = make_int2(src[e], __float_as_int(ea[e]));
        eb_dst[pos] = d;
    }
}

// ---------------- phase C: per-bucket CSR build + degw (LDS atomics only) ----------------
__global__ __launch_bounds__(512) void bucket_kernel(
    const int* __restrict__ bkt_ptr, const int2* __restrict__ eb_sea,
    const int* __restrict__ eb_dst,
    int* __restrict__ row_ptr, float* __restrict__ degw, int2* __restrict__ epack) {
    __shared__ int cnt[BKT_SZ];
    __shared__ float dws[BKT_SZ];
    __shared__ int s[BKT_SZ];
    __shared__ int cur[BKT_SZ];
    int k = blockIdx.x, t = threadIdx.x;
    int base = k << BKT_BITS;
    int nn = N_NODES - base;
    if (nn > BKT_SZ) nn = BKT_SZ;
    cnt[t] = 0;
    dws[t] = 0.0f;
    __syncthreads();
    int beg = bkt_ptr[k], end = bkt_ptr[k + 1];
    for (int j = beg + t; j < end; j += 512) {
        int d = eb_dst[j] - base;
        atomicAdd(cnt + d, 1);
        atomicAdd(dws + d, __int_as_float(eb_sea[j].y));
    }
    __syncthreads();
    s[t] = cnt[t];
    for (int off = 1; off < 512; off <<= 1) {
        __syncthreads();
        int tv = (t >= off) ? s[t - off] : 0;
        __syncthreads();
        s[t] += tv;
    }
    __syncthreads();
    int rstart = beg + s[t] - cnt[t];
    if (t < nn) {
        row_ptr[base + t] = rstart;
        degw[base + t] = dws[t];
        cur[t] = rstart;
    }
    __syncthreads();
    for (int j = beg + t; j < end; j += 512) {
        int2 se = eb_sea[j];
        int d = eb_dst[j] - base;
        int pos = atomicAdd(cur + d, 1);
        epack[pos] = se;
    }
    if (k == NBKT - 1 && t == 0) row_ptr[N_NODES] = N_EDGES;
}

// ---------------- linA: a = h@W1 + b1  (split-bf16 MFMA) ----------------
__global__ __launch_bounds__(256) void linA_kernel(
    const float* __restrict__ h, const float* __restrict__ W1,
    const float* __restrict__ bias1, float* __restrict__ a) {
    __shared__ alignas(16) unsigned short whi[H * LROW];   // [f][k] transposed
    __shared__ alignas(16) unsigned short wlo[H * LROW];
    __shared__ alignas(16) unsigned short ahi[64 * LROW];  // [n_local][k]
    __shared__ alignas(16) unsigned short alo[64 * LROW];
    int t = threadIdx.x;
    for (int i = t; i < H * H; i += 256) {
        int k = i >> 6, f = i & 63;
        float w = W1[i];
        unsigned short hi = f2bf(w);
        whi[f * LROW + k] = hi;
        wlo[f * LROW + k] = f2bf(w - bf2f(hi));
    }
    int wv = t >> 6, lane = t & 63;
    int quad = lane >> 4, m16 = lane & 15;
    for (int chunk = blockIdx.x; chunk < NCHUNKS; chunk += gridDim.x) {
        int nbase = chunk * 64;
        __syncthreads();  // protect LDS reuse across iterations (and weight staging, 1st iter)
        for (int i = t; i < 64 * H; i += 256) {
            int nl = i >> 6, k = i & 63;
            int n = nbase + nl;
            float v = (n < N_NODES) ? h[(size_t)n * H + k] : 0.0f;
            unsigned short hi = f2bf(v);
            ahi[nl * LROW + k] = hi;
            alo[nl * LROW + k] = f2bf(v - bf2f(hi));
        }
        __syncthreads();
        int abase = (wv * 16 + m16) * LROW + quad * 8;
        bf16x8 Ah0 = *(const bf16x8*)&ahi[abase];
        bf16x8 Ah1 = *(const bf16x8*)&ahi[abase + 32];
        bf16x8 Al0 = *(const bf16x8*)&alo[abase];
        bf16x8 Al1 = *(const bf16x8*)&alo[abase + 32];
#pragma unroll
        for (int tt = 0; tt < 4; ++tt) {
            floatx4 acc = {0.f, 0.f, 0.f, 0.f};
            int bbase = (tt * 16 + m16) * LROW + quad * 8;
            bf16x8 Bh0 = *(const bf16x8*)&whi[bbase];
            bf16x8 Bl0 = *(const bf16x8*)&wlo[bbase];
            bf16x8 Bh1 = *(const bf16x8*)&whi[bbase + 32];
            bf16x8 Bl1 = *(const bf16x8*)&wlo[bbase + 32];
            acc = __builtin_amdgcn_mfma_f32_16x16x32_bf16(Ah0, Bh0, acc, 0, 0, 0);
            acc = __builtin_amdgcn_mfma_f32_16x16x32_bf16(Ah0, Bl0, acc, 0, 0, 0);
            acc = __builtin_amdgcn_mfma_f32_16x16x32_bf16(Al0, Bh0, acc, 0, 0, 0);
            acc = __builtin_amdgcn_mfma_f32_16x16x32_bf16(Ah1, Bh1, acc, 0, 0, 0);
            acc = __builtin_amdgcn_mfma_f32_16x16x32_bf16(Ah1, Bl1, acc, 0, 0, 0);
            acc = __builtin_amdgcn_mfma_f32_16x16x32_bf16(Al1, Bh1, acc, 0, 0, 0);
            int f = tt * 16 + m16;
            float bb = bias1[f];
            int nrow = nbase + wv * 16 + quad * 4;
#pragma unroll
            for (int r = 0; r < 4; ++r) {
                int n = nrow + r;
                if (n < N_NODES) a[(size_t)n * H + f] = acc[r] + bb;
            }
        }
    }
}

// ---------------- linB: agg = h@W3 + b3 - (h@W2)*degw  (split-bf16 MFMA) ----------------
__global__ __launch_bounds__(256) void linB_kernel(
    const float* __restrict__ h, const float* __restrict__ degw,
    const float* __restrict__ W2, const float* __restrict__ W3,
    const float* __restrict__ bias3, float* __restrict__ agg) {
    __shared__ alignas(16) unsigned short w2hi[H * LROW];
    __shared__ alignas(16) unsigned short w2lo[H * LROW];
    __shared__ alignas(16) unsigned short w3hi[H * LROW];
    __shared__ alignas(16) unsigned short w3lo[H * LROW];
    __shared__ alignas(16) unsigned short ahi[64 * LROW];
    __shared__ alignas(16) unsigned short alo[64 * LROW];
    int t = threadIdx.x;
    for (int i = t; i < H * H; i += 256) {
        int k = i >> 6, f = i & 63;
        float w2 = W2[i], w3 = W3[i];
        unsigned short h2 = f2bf(w2), h3 = f2bf(w3);
        w2hi[f * LROW + k] = h2;
        w2lo[f * LROW + k] = f2bf(w2 - bf2f(h2));
        w3hi[f * LROW + k] = h3;
        w3lo[f * LROW + k] = f2bf(w3 - bf2f(h3));
    }
    int wv = t >> 6, lane = t & 63;
    int quad = lane >> 4, m16 = lane & 15;
    for (int chunk = blockIdx.x; chunk < NCHUNKS; chunk += gridDim.x) {
        int nbase = chunk * 64;
        __syncthreads();
        for (int i = t; i < 64 * H; i += 256) {
            int nl = i >> 6, k = i & 63;
            int n = nbase + nl;
            float v = (n < N_NODES) ? h[(size_t)n * H + k] : 0.0f;
            unsigned short hi = f2bf(v);
            ahi[nl * LROW + k] = hi;
            alo[nl * LROW + k] = f2bf(v - bf2f(hi));
        }
        __syncthreads();
        int abase = (wv * 16 + m16) * LROW + quad * 8;
        bf16x8 Ah0 = *(const bf16x8*)&ahi[abase];
        bf16x8 Ah1 = *(const bf16x8*)&ahi[abase + 32];
        bf16x8 Al0 = *(const bf16x8*)&alo[abase];
        bf16x8 Al1 = *(const bf16x8*)&alo[abase + 32];
        int nrow = nbase + wv * 16 + quad * 4;
        float dw[4];
#pragma unroll
        for (int r = 0; r < 4; ++r)
            dw[r] = (nrow + r < N_NODES) ? degw[nrow + r] : 0.0f;
#pragma unroll
        for (int tt = 0; tt < 4; ++tt) {
            floatx4 acc2 = {0.f, 0.f, 0.f, 0.f};
            floatx4 acc3 = {0.f, 0.f, 0.f, 0.f};
            int bbase = (tt * 16 + m16) * LROW + quad * 8;
            {
                bf16x8 B2h = *(const bf16x8*)&w2hi[bbase];
                bf16x8 B2l = *(const bf16x8*)&w2lo[bbase];
                bf16x8 B3h = *(const bf16x8*)&w3hi[bbase];
                bf16x8 B3l = *(const bf16x8*)&w3lo[bbase];
                acc2 = __builtin_amdgcn_mfma_f32_16x16x32_bf16(Ah0, B2h, acc2, 0, 0, 0);
                acc2 = __builtin_amdgcn_mfma_f32_16x16x32_bf16(Ah0, B2l, acc2, 0, 0, 0);
                acc2 = __builtin_amdgcn_mfma_f32_16x16x32_bf16(Al0, B2h, acc2, 0, 0, 0);
                acc3 = __builtin_amdgcn_mfma_f32_16x16x32_bf16(Ah0, B3h, acc3, 0, 0, 0);
                acc3 = __builtin_amdgcn_mfma_f32_16x16x32_bf16(Ah0, B3l, acc3, 0, 0, 0);
                acc3 = __builtin_amdgcn_mfma_f32_16x16x32_bf16(Al0, B3h, acc3, 0, 0, 0);
            }
            {
                bf16x8 B2h = *(const bf16x8*)&w2hi[bbase + 32];
                bf16x8 B2l = *(const bf16x8*)&w2lo[bbase + 32];
                bf16x8 B3h = *(const bf16x8*)&w3hi[bbase + 32];
                bf16x8 B3l = *(const bf16x8*)&w3lo[bbase + 32];
                acc2 = __builtin_amdgcn_mfma_f32_16x16x32_bf16(Ah1, B2h, acc2, 0, 0, 0);
                acc2 = __builtin_amdgcn_mfma_f32_16x16x32_bf16(Ah1, B2l, acc2, 0, 0, 0);
                acc2 = __builtin_amdgcn_mfma_f32_16x16x32_bf16(Al1, B2h, acc2, 0, 0, 0);
                acc3 = __builtin_amdgcn_mfma_f32_16x16x32_bf16(Ah1, B3h, acc3, 0, 0, 0);
                acc3 = __builtin_amdgcn_mfma_f32_16x16x32_bf16(Ah1, B3l, acc3, 0, 0, 0);
                acc3 = __builtin_amdgcn_mfma_f32_16x16x32_bf16(Al1, B3h, acc3, 0, 0, 0);
            }
            int f = tt * 16 + m16;
            float bb = bias3[f];
#pragma unroll
            for (int r = 0; r < 4; ++r) {
                int n = nrow + r;
                if (n < N_NODES) agg[(size_t)n * H + f] = acc3[r] + bb - acc2[r] * dw[r];
            }
        }
    }
}

// ---------------- gather: h[d] = relu(agg_init[d] + sum_in ea*a[src]) ----------------
__global__ __launch_bounds__(256) void gather_kernel(
    const int* __restrict__ row_ptr, const int2* __restrict__ epack,
    const float* __restrict__ a, const float* __restrict__ agg_init,
    float* __restrict__ h) {
    int n = blockIdx.x * 4 + (threadIdx.x >> 6);
    if (n >= N_NODES) return;
    int f = threadIdx.x & 63;
    int beg = row_ptr[n], end = row_ptr[n + 1];
    float acc = agg_init[(size_t)n * H + f];
    int j = beg;
    for (; j + 3 < end; j += 4) {
        int2 p0 = epack[j], p1 = epack[j + 1], p2 = epack[j + 2], p3 = epack[j + 3];
        float a0 = a[(size_t)p0.x * H + f];
        float a1 = a[(size_t)p1.x * H + f];
        float a2 = a[(size_t)p2.x * H + f];
        float a3 = a[(size_t)p3.x * H + f];
        acc += __int_as_float(p0.y) * a0;
        acc += __int_as_float(p1.y) * a1;
        acc += __int_as_float(p2.y) * a2;
        acc += __int_as_float(p3.y) * a3;
    }
    for (; j < end; ++j) {
        int2 p = epack[j];
        acc += __int_as_float(p.y) * a[(size_t)p.x * H + f];
    }
    h[(size_t)n * H + f] = fmaxf(acc, 0.0f);
}

// ---------------- fused mean-pool + MLP head (batch is sorted) ----------------
__device__ __forceinline__ int lower_bound(const int* __restrict__ arr, int n, int key) {
    int lo = 0, hi = n;
    while (lo < hi) {
        int mid = (lo + hi) >> 1;
        if (arr[mid] < key) lo = mid + 1; else hi = mid;
    }
    return lo;
}

__global__ __launch_bounds__(128) void poolhead_kernel(
    const float* __restrict__ h, const int* __restrict__ batch,
    const float* __restrict__ Wf1, const float* __restrict__ bf1v,
    const float* __restrict__ Wf2, const float* __restrict__ bf2v,
    float* __restrict__ out) {
    __shared__ float psum[128];
    __shared__ float gx[H];
    __shared__ float hid[2 * H];
    int g = blockIdx.x, t = threadIdx.x;
    int s = lower_bound(batch, N_NODES, g);
    int e = lower_bound(batch, N_NODES, g + 1);
    int w = t >> 6, f = t & 63;
    float accf = 0.0f;
    for (int n = s + w; n < e; n += 2) accf += h[(size_t)n * H + f];
    psum[t] = accf;
    __syncthreads();
    if (t < H) {
        float c = (float)(e - s);
        gx[t] = (psum[t] + psum[t + 64]) / fmaxf(c, 1.0f);
    }
    __syncthreads();
    float acc = bf1v[t];
    for (int k = 0; k < H; ++k) acc += gx[k] * Wf1[k * 2 * H + t];
    hid[t] = fmaxf(acc, 0.0f);
    __syncthreads();
    if (t < NUM_CLASS) {
        float o = bf2v[t];
        for (int k = 0; k < 2 * H; ++k) o += hid[k] * Wf2[k * NUM_CLASS + t];
        out[g * NUM_CLASS + t] = o;
    }
}

extern "C" void kernel_launch(void* const* d_in, const int* in_sizes, int n_in,
                              void* d_out, int out_size, void* d_ws, size_t ws_size,
                              hipStream_t stream) {
    const float* x    = (const float*)d_in[0];
    const int*  ei    = (const int*)d_in[1];
    const int*  batch = (const int*)d_in[2];
    const float* ea   = (const float*)d_in[3];
    const float* Wemb = (const float*)d_in[4];
    const float* bemb = (const float*)d_in[5];
    const float* pW1  = (const float*)d_in[6];
    const float* pb1  = (const float*)d_in[7];
    const float* pW2  = (const float*)d_in[8];
    const float* pW3  = (const float*)d_in[9];
    const float* pb3  = (const float*)d_in[10];
    const float* Wf1  = (const float*)d_in[11];
    const float* bf1v = (const float*)d_in[12];
    const float* Wf2  = (const float*)d_in[13];
    const float* bf2v = (const float*)d_in[14];
    float* out = (float*)d_out;

    const int* src = ei;
    const int* dst = ei + N_EDGES;

    // ---- workspace layout ----
    const size_t NH = (size_t)N_NODES * H;
    float* h        = (float*)d_ws;                     // NH floats
    float* a        = h + NH;                           // NH floats
    float* agg      = a + NH;                           // NH floats
    int2*  epack    = (int2*)(agg + NH);                // N_EDGES int2
    int*   histM    = (int*)(epack + N_EDGES);          // MHIST
    int*   incl     = histM + MHIST;                    // MHIST
    int*   ebase    = incl + MHIST;                     // MHIST
    int*   partials = ebase + MHIST;                    // pad 512
    int*   chunk_off= partials + 512;                   // 512
    int*   bkt_ptr  = chunk_off + 512;                  // NBKT+1
    int*   row_ptr  = bkt_ptr + NBKT + 1;               // N_NODES+1
    float* degw     = (float*)(row_ptr + N_NODES + 1);  // N_NODES
    // staging overlays a/agg (dead until lin kernels; build completes first)
    int2*  eb_sea   = (int2*)a;                         // N_EDGES int2
    int*   eb_dst   = (int*)agg;                        // N_EDGES int

    // ---- CSR build: two-level LDS-atomic counting sort (no global atomics) ----
    hist1_kernel<<<NBLK, 256, 0, stream>>>(dst, histM);
    gscan1_kernel<<<MHIST / 512, 512, 0, stream>>>(histM, incl, partials);
    gscan2_kernel<<<1, 512, 0, stream>>>(partials, chunk_off, MHIST / 512);
    gscan3_kernel<<<(MHIST + 255) / 256, 256, 0, stream>>>(histM, incl, chunk_off, ebase, bkt_ptr);
    scatter1_kernel<<<NBLK, 256, 0, stream>>>(src, dst, ea, ebase, eb_sea, eb_dst);
    bucket_kernel<<<NBKT, 512, 0, stream>>>(bkt_ptr, eb_sea, eb_dst, row_ptr, degw, epack);

    embed_kernel<<<(N_NODES * H + 255) / 256, 256, 0, stream>>>(x, Wemb, bemb, h);

    for (int l = 0; l < LAYERS; ++l) {
        linA_kernel<<<1024, 256, 0, stream>>>(
            h, pW1 + (size_t)l * H * H, pb1 + (size_t)l * H, a);
        linB_kernel<<<512, 256, 0, stream>>>(
            h, degw, pW2 + (size_t)l * H * H,
            pW3 + (size_t)l * H * H, pb3 + (size_t)l * H, agg);
        gather_kernel<<<(N_NODES + 3) / 4, 256, 0, stream>>>(row_ptr, epack, a, agg, h);
    }

    poolhead_kernel<<<N_GRAPHS, 2 * H, 0, stream>>>(h, batch, Wf1, bf1v, Wf2, bf2v, out);
}

// Round 7
// 479.692 us; speedup vs baseline: 3.2920x; 1.2212x over previous
//
#include <hip/hip_runtime.h>

#define N_NODES 100000
#define N_EDGES 1600000
#define N_GRAPHS 512
#define X_DIM 4
#define H 64
#define LAYERS 3
#define NUM_CLASS 3
#define NBLK 256            // partition blocks
#define EPB (N_EDGES / NBLK)  // 6250 edges per partition block
#define BKT_BITS 9
#define BKT_SZ 512          // nodes per bucket
#define NBKT ((N_NODES + BKT_SZ - 1) / BKT_SZ)  // 196
#define MHIST (NBKT * NBLK)  // 50176, divisible by 512
#define LROW 72             // padded LDS row (shorts): 144 B = 16B-aligned per row
#define NCHUNKS ((N_NODES + 63) / 64)  // 1563

typedef unsigned short ushort;
typedef short bf16x8 __attribute__((ext_vector_type(8)));
typedef unsigned short ush8 __attribute__((ext_vector_type(8)));
typedef float floatx4 __attribute__((ext_vector_type(4)));

__device__ __forceinline__ ushort f2bf(float v) {
    unsigned u = __float_as_uint(v);
    unsigned r = (u + 0x7fff + ((u >> 16) & 1)) >> 16;  // round-nearest-even
    return (ushort)r;
}
__device__ __forceinline__ float bf2f(ushort s) {
    return __uint_as_float(((unsigned)s) << 16);
}

// ---------------- embed: h = bf16(x @ Wemb + bemb) ----------------
__global__ void embed_kernel(const float* __restrict__ x, const float* __restrict__ Wemb,
                             const float* __restrict__ bemb, ushort* __restrict__ h) {
    int i = blockIdx.x * blockDim.x + threadIdx.x;
    if (i >= N_NODES * H) return;
    int n = i >> 6, f = i & 63;
    float acc = bemb[f];
#pragma unroll
    for (int k = 0; k < X_DIM; ++k)
        acc += x[n * X_DIM + k] * Wemb[k * H + f];
    h[i] = f2bf(acc);
}

// ---------------- phase A: per-block bucket histogram (LDS atomics only) ----------------
__global__ __launch_bounds__(256) void hist1_kernel(const int* __restrict__ dst,
                                                    int* __restrict__ histM) {
    __shared__ int hist[NBKT];
    int t = threadIdx.x, b = blockIdx.x;
    for (int i = t; i < NBKT; i += 256) hist[i] = 0;
    __syncthreads();
    int e0 = b * EPB;
    for (int j = t; j < EPB; j += 256) {
        int d = dst[e0 + j];
        atomicAdd(hist + (d >> BKT_BITS), 1);
    }
    __syncthreads();
    for (int i = t; i < NBKT; i += 256) histM[i * NBLK + b] = hist[i];
}

// ---------------- generic scan over MHIST entries ----------------
__global__ __launch_bounds__(512) void gscan1_kernel(const int* __restrict__ v,
                                                     int* __restrict__ incl,
                                                     int* __restrict__ partials) {
    __shared__ int s[512];
    int tid = threadIdx.x;
    int i = blockIdx.x * 512 + tid;
    int x = (i < MHIST) ? v[i] : 0;
    s[tid] = x;
    for (int off = 1; off < 512; off <<= 1) {
        __syncthreads();
        int tv = (tid >= off) ? s[tid - off] : 0;
        __syncthreads();
        s[tid] += tv;
    }
    __syncthreads();
    if (i < MHIST) incl[i] = s[tid];
    if (tid == 511) partials[blockIdx.x] = s[tid];
}

__global__ __launch_bounds__(512) void gscan2_kernel(const int* __restrict__ partials,
                                                     int* __restrict__ chunk_off, int nchunk) {
    __shared__ int s[512];
    int tid = threadIdx.x;
    s[tid] = (tid < nchunk) ? partials[tid] : 0;
    for (int off = 1; off < 512; off <<= 1) {
        __syncthreads();
        int tv = (tid >= off) ? s[tid - off] : 0;
        __syncthreads();
        s[tid] += tv;
    }
    __syncthreads();
    int excl = (tid == 0) ? 0 : s[tid - 1];
    __syncthreads();
    if (tid < nchunk) chunk_off[tid] = excl;
}

__global__ void gscan3_kernel(const int* __restrict__ v, const int* __restrict__ incl,
                              const int* __restrict__ chunk_off,
                              int* __restrict__ ebase, int* __restrict__ bkt_ptr) {
    int i = blockIdx.x * 256 + threadIdx.x;
    if (i >= MHIST) return;
    int e = incl[i] + chunk_off[i >> 9] - v[i];
    ebase[i] = e;
    if ((i & (NBLK - 1)) == 0) bkt_ptr[i / NBLK] = e;
    if (i == MHIST - 1) bkt_ptr[NBKT] = e + v[i];
}

// ---------------- phase B: partition edges into bucket order (LDS cursors) ----------------
// packed edge word: src (17 bits) << 15 | bf16(ea) low 15 bits (sign always 0)
__global__ __launch_bounds__(256) void scatter1_kernel(
    const int* __restrict__ src, const int* __restrict__ dst, const float* __restrict__ ea,
    const int* __restrict__ ebase, unsigned* __restrict__ eb_se, int* __restrict__ eb_dst) {
    __shared__ int cur[NBKT];
    int t = threadIdx.x, b = blockIdx.x;
    for (int i = t; i < NBKT; i += 256) cur[i] = ebase[i * NBLK + b];
    __syncthreads();
    int e0 = b * EPB;
    for (int j = t; j < EPB; j += 256) {
        int e = e0 + j;
        int d = dst[e];
        int k = d >> BKT_BITS;
        int pos = atomicAdd(cur + k, 1);
        eb_se[pos] = ((unsigned)src[e] << 15) | (unsigned)f2bf(ea[e]);
        eb_dst[pos] = d;
    }
}

// ---------------- phase C: per-bucket CSR build + degw (LDS atomics only) ----------------
__global__ __launch_bounds__(512) void bucket_kernel(
    const int* __restrict__ bkt_ptr, const unsigned* __restrict__ eb_se,
    const int* __restrict__ eb_dst,
    int* __restrict__ row_ptr, float* __restrict__ degw, unsigned* __restrict__ epack) {
    __shared__ int cnt[BKT_SZ];
    __shared__ float dws[BKT_SZ];
    __shared__ int s[BKT_SZ];
    __shared__ int cur[BKT_SZ];
    int k = blockIdx.x, t = threadIdx.x;
    int base = k << BKT_BITS;
    int nn = N_NODES - base;
    if (nn > BKT_SZ) nn = BKT_SZ;
    cnt[t] = 0;
    dws[t] = 0.0f;
    __syncthreads();
    int beg = bkt_ptr[k], end = bkt_ptr[k + 1];
    for (int j = beg + t; j < end; j += 512) {
        int d = eb_dst[j] - base;
        atomicAdd(cnt + d, 1);
        atomicAdd(dws + d, __uint_as_float((eb_se[j] & 0x7FFFu) << 16));
    }
    __syncthreads();
    s[t] = cnt[t];
    for (int off = 1; off < 512; off <<= 1) {
        __syncthreads();
        int tv = (t >= off) ? s[t - off] : 0;
        __syncthreads();
        s[t] += tv;
    }
    __syncthreads();
    int rstart = beg + s[t] - cnt[t];
    if (t < nn) {
        row_ptr[base + t] = rstart;
        degw[base + t] = dws[t];
        cur[t] = rstart;
    }
    __syncthreads();
    for (int j = beg + t; j < end; j += 512) {
        unsigned se = eb_se[j];
        int d = eb_dst[j] - base;
        int pos = atomicAdd(cur + d, 1);
        epack[pos] = se;
    }
    if (k == NBKT - 1 && t == 0) row_ptr[N_NODES] = N_EDGES;
}

// ---------------- linA: a = bf16(h@W1 + b1)  (bf16 h x split-bf16 W, MFMA) ----------------
__global__ __launch_bounds__(256) void linA_kernel(
    const ushort* __restrict__ h, const float* __restrict__ W1,
    const float* __restrict__ bias1, ushort* __restrict__ a) {
    __shared__ alignas(16) ushort whi[H * LROW];   // [f][k] transposed
    __shared__ alignas(16) ushort wlo[H * LROW];
    __shared__ alignas(16) ushort ah[64 * LROW];   // [n_local][k]
    int t = threadIdx.x;
    for (int i = t; i < H * H; i += 256) {
        int k = i >> 6, f = i & 63;
        float w = W1[i];
        ushort hi = f2bf(w);
        whi[f * LROW + k] = hi;
        wlo[f * LROW + k] = f2bf(w - bf2f(hi));
    }
    int wv = t >> 6, lane = t & 63;
    int quad = lane >> 4, m16 = lane & 15;
    for (int chunk = blockIdx.x; chunk < NCHUNKS; chunk += gridDim.x) {
        int nbase = chunk * 64;
        __syncthreads();  // protect LDS reuse across iterations (and weight staging)
        for (int v = t; v < 64 * 8; v += 256) {   // 512 x 8-short vectors
            int nl = v >> 3, k0 = (v & 7) * 8;
            int n = nbase + nl;
            ush8 val = {0, 0, 0, 0, 0, 0, 0, 0};
            if (n < N_NODES) val = *(const ush8*)&h[(size_t)n * H + k0];
            *(ush8*)&ah[nl * LROW + k0] = val;
        }
        __syncthreads();
        int abase = (wv * 16 + m16) * LROW + quad * 8;
        bf16x8 Ah0 = *(const bf16x8*)&ah[abase];
        bf16x8 Ah1 = *(const bf16x8*)&ah[abase + 32];
#pragma unroll
        for (int tt = 0; tt < 4; ++tt) {
            floatx4 acc = {0.f, 0.f, 0.f, 0.f};
            int bbase = (tt * 16 + m16) * LROW + quad * 8;
            bf16x8 Bh0 = *(const bf16x8*)&whi[bbase];
            bf16x8 Bl0 = *(const bf16x8*)&wlo[bbase];
            bf16x8 Bh1 = *(const bf16x8*)&whi[bbase + 32];
            bf16x8 Bl1 = *(const bf16x8*)&wlo[bbase + 32];
            acc = __builtin_amdgcn_mfma_f32_16x16x32_bf16(Ah0, Bh0, acc, 0, 0, 0);
            acc = __builtin_amdgcn_mfma_f32_16x16x32_bf16(Ah0, Bl0, acc, 0, 0, 0);
            acc = __builtin_amdgcn_mfma_f32_16x16x32_bf16(Ah1, Bh1, acc, 0, 0, 0);
            acc = __builtin_amdgcn_mfma_f32_16x16x32_bf16(Ah1, Bl1, acc, 0, 0, 0);
            int f = tt * 16 + m16;
            float bb = bias1[f];
            int nrow = nbase + wv * 16 + quad * 4;
#pragma unroll
            for (int r = 0; r < 4; ++r) {
                int n = nrow + r;
                if (n < N_NODES) a[(size_t)n * H + f] = f2bf(acc[r] + bb);
            }
        }
    }
}

// ---------------- linB: agg = h@W3 + b3 - (h@W2)*degw  (f32 out) ----------------
__global__ __launch_bounds__(256) void linB_kernel(
    const ushort* __restrict__ h, const float* __restrict__ degw,
    const float* __restrict__ W2, const float* __restrict__ W3,
    const float* __restrict__ bias3, float* __restrict__ agg) {
    __shared__ alignas(16) ushort w2hi[H * LROW];
    __shared__ alignas(16) ushort w2lo[H * LROW];
    __shared__ alignas(16) ushort w3hi[H * LROW];
    __shared__ alignas(16) ushort w3lo[H * LROW];
    __shared__ alignas(16) ushort ah[64 * LROW];
    int t = threadIdx.x;
    for (int i = t; i < H * H; i += 256) {
        int k = i >> 6, f = i & 63;
        float w2 = W2[i], w3 = W3[i];
        ushort h2 = f2bf(w2), h3 = f2bf(w3);
        w2hi[f * LROW + k] = h2;
        w2lo[f * LROW + k] = f2bf(w2 - bf2f(h2));
        w3hi[f * LROW + k] = h3;
        w3lo[f * LROW + k] = f2bf(w3 - bf2f(h3));
    }
    int wv = t >> 6, lane = t & 63;
    int quad = lane >> 4, m16 = lane & 15;
    for (int chunk = blockIdx.x; chunk < NCHUNKS; chunk += gridDim.x) {
        int nbase = chunk * 64;
        __syncthreads();
        for (int v = t; v < 64 * 8; v += 256) {
            int nl = v >> 3, k0 = (v & 7) * 8;
            int n = nbase + nl;
            ush8 val = {0, 0, 0, 0, 0, 0, 0, 0};
            if (n < N_NODES) val = *(const ush8*)&h[(size_t)n * H + k0];
            *(ush8*)&ah[nl * LROW + k0] = val;
        }
        __syncthreads();
        int abase = (wv * 16 + m16) * LROW + quad * 8;
        bf16x8 Ah0 = *(const bf16x8*)&ah[abase];
        bf16x8 Ah1 = *(const bf16x8*)&ah[abase + 32];
        int nrow = nbase + wv * 16 + quad * 4;
        float dw[4];
#pragma unroll
        for (int r = 0; r < 4; ++r)
            dw[r] = (nrow + r < N_NODES) ? degw[nrow + r] : 0.0f;
#pragma unroll
        for (int tt = 0; tt < 4; ++tt) {
            floatx4 acc2 = {0.f, 0.f, 0.f, 0.f};
            floatx4 acc3 = {0.f, 0.f, 0.f, 0.f};
            int bbase = (tt * 16 + m16) * LROW + quad * 8;
            {
                bf16x8 B2h = *(const bf16x8*)&w2hi[bbase];
                bf16x8 B2l = *(const bf16x8*)&w2lo[bbase];
                bf16x8 B3h = *(const bf16x8*)&w3hi[bbase];
                bf16x8 B3l = *(const bf16x8*)&w3lo[bbase];
                acc2 = __builtin_amdgcn_mfma_f32_16x16x32_bf16(Ah0, B2h, acc2, 0, 0, 0);
                acc2 = __builtin_amdgcn_mfma_f32_16x16x32_bf16(Ah0, B2l, acc2, 0, 0, 0);
                acc3 = __builtin_amdgcn_mfma_f32_16x16x32_bf16(Ah0, B3h, acc3, 0, 0, 0);
                acc3 = __builtin_amdgcn_mfma_f32_16x16x32_bf16(Ah0, B3l, acc3, 0, 0, 0);
            }
            {
                bf16x8 B2h = *(const bf16x8*)&w2hi[bbase + 32];
                bf16x8 B2l = *(const bf16x8*)&w2lo[bbase + 32];
                bf16x8 B3h = *(const bf16x8*)&w3hi[bbase + 32];
                bf16x8 B3l = *(const bf16x8*)&w3lo[bbase + 32];
                acc2 = __builtin_amdgcn_mfma_f32_16x16x32_bf16(Ah1, B2h, acc2, 0, 0, 0);
                acc2 = __builtin_amdgcn_mfma_f32_16x16x32_bf16(Ah1, B2l, acc2, 0, 0, 0);
                acc3 = __builtin_amdgcn_mfma_f32_16x16x32_bf16(Ah1, B3h, acc3, 0, 0, 0);
                acc3 = __builtin_amdgcn_mfma_f32_16x16x32_bf16(Ah1, B3l, acc3, 0, 0, 0);
            }
            int f = tt * 16 + m16;
            float bb = bias3[f];
#pragma unroll
            for (int r = 0; r < 4; ++r) {
                int n = nrow + r;
                if (n < N_NODES) agg[(size_t)n * H + f] = acc3[r] + bb - acc2[r] * dw[r];
            }
        }
    }
}

// ---------------- gather: h[d] = bf16(relu(agg_init[d] + sum_in ea*a[src])) ----------------
__global__ __launch_bounds__(256) void gather_kernel(
    const int* __restrict__ row_ptr, const unsigned* __restrict__ epack,
    const ushort* __restrict__ a, const float* __restrict__ agg_init,
    ushort* __restrict__ h) {
    int n = blockIdx.x * 4 + (threadIdx.x >> 6);
    if (n >= N_NODES) return;
    int f = threadIdx.x & 63;
    int beg = row_ptr[n], end = row_ptr[n + 1];
    float acc = agg_init[(size_t)n * H + f];
    int j = beg;
    for (; j + 3 < end; j += 4) {
        unsigned w0 = epack[j], w1 = epack[j + 1], w2 = epack[j + 2], w3 = epack[j + 3];
        float a0 = bf2f(a[(size_t)(w0 >> 15) * H + f]);
        float a1 = bf2f(a[(size_t)(w1 >> 15) * H + f]);
        float a2 = bf2f(a[(size_t)(w2 >> 15) * H + f]);
        float a3 = bf2f(a[(size_t)(w3 >> 15) * H + f]);
        acc += __uint_as_float((w0 & 0x7FFFu) << 16) * a0;
        acc += __uint_as_float((w1 & 0x7FFFu) << 16) * a1;
        acc += __uint_as_float((w2 & 0x7FFFu) << 16) * a2;
        acc += __uint_as_float((w3 & 0x7FFFu) << 16) * a3;
    }
    for (; j < end; ++j) {
        unsigned w = epack[j];
        acc += __uint_as_float((w & 0x7FFFu) << 16) * bf2f(a[(size_t)(w >> 15) * H + f]);
    }
    h[(size_t)n * H + f] = f2bf(fmaxf(acc, 0.0f));
}

// ---------------- fused mean-pool + MLP head (batch is sorted) ----------------
__device__ __forceinline__ int lower_bound(const int* __restrict__ arr, int n, int key) {
    int lo = 0, hi = n;
    while (lo < hi) {
        int mid = (lo + hi) >> 1;
        if (arr[mid] < key) lo = mid + 1; else hi = mid;
    }
    return lo;
}

__global__ __launch_bounds__(128) void poolhead_kernel(
    const ushort* __restrict__ h, const int* __restrict__ batch,
    const float* __restrict__ Wf1, const float* __restrict__ bf1v,
    const float* __restrict__ Wf2, const float* __restrict__ bf2v,
    float* __restrict__ out) {
    __shared__ float psum[128];
    __shared__ float gx[H];
    __shared__ float hid[2 * H];
    int g = blockIdx.x, t = threadIdx.x;
    int s = lower_bound(batch, N_NODES, g);
    int e = lower_bound(batch, N_NODES, g + 1);
    int w = t >> 6, f = t & 63;
    float accf = 0.0f;
    for (int n = s + w; n < e; n += 2) accf += bf2f(h[(size_t)n * H + f]);
    psum[t] = accf;
    __syncthreads();
    if (t < H) {
        float c = (float)(e - s);
        gx[t] = (psum[t] + psum[t + 64]) / fmaxf(c, 1.0f);
    }
    __syncthreads();
    float acc = bf1v[t];
    for (int k = 0; k < H; ++k) acc += gx[k] * Wf1[k * 2 * H + t];
    hid[t] = fmaxf(acc, 0.0f);
    __syncthreads();
    if (t < NUM_CLASS) {
        float o = bf2v[t];
        for (int k = 0; k < 2 * H; ++k) o += hid[k] * Wf2[k * NUM_CLASS + t];
        out[g * NUM_CLASS + t] = o;
    }
}

extern "C" void kernel_launch(void* const* d_in, const int* in_sizes, int n_in,
                              void* d_out, int out_size, void* d_ws, size_t ws_size,
                              hipStream_t stream) {
    const float* x    = (const float*)d_in[0];
    const int*  ei    = (const int*)d_in[1];
    const int*  batch = (const int*)d_in[2];
    const float* ea   = (const float*)d_in[3];
    const float* Wemb = (const float*)d_in[4];
    const float* bemb = (const float*)d_in[5];
    const float* pW1  = (const float*)d_in[6];
    const float* pb1  = (const float*)d_in[7];
    const float* pW2  = (const float*)d_in[8];
    const float* pW3  = (const float*)d_in[9];
    const float* pb3  = (const float*)d_in[10];
    const float* Wf1  = (const float*)d_in[11];
    const float* bf1v = (const float*)d_in[12];
    const float* Wf2  = (const float*)d_in[13];
    const float* bf2v = (const float*)d_in[14];
    float* out = (float*)d_out;

    const int* src = ei;
    const int* dst = ei + N_EDGES;

    // ---- workspace layout ----
    const size_t NH = (size_t)N_NODES * H;
    char* p = (char*)d_ws;
    ushort* h       = (ushort*)p;            p += NH * 2;           // 12.8 MB
    ushort* a       = (ushort*)p;            p += NH * 2;           // 12.8 MB
    float*  agg     = (float*)p;             p += NH * 4;           // 25.6 MB
    unsigned* epack = (unsigned*)p;          p += (size_t)N_EDGES * 4;  // 6.4 MB
    int*   histM    = (int*)p;               p += MHIST * 4;
    int*   incl     = (int*)p;               p += MHIST * 4;
    int*   ebase    = (int*)p;               p += MHIST * 4;
    int*   partials = (int*)p;               p += 512 * 4;
    int*   chunk_off= (int*)p;               p += 512 * 4;
    int*   bkt_ptr  = (int*)p;               p += (NBKT + 1) * 4;
    int*   row_ptr  = (int*)p;               p += (N_NODES + 1) * 4;
    float* degw     = (float*)p;             p += N_NODES * 4;
    // staging overlays a/agg (dead until lin kernels; build completes first)
    unsigned* eb_se = (unsigned*)a;          // 6.4 MB  (a region: 12.8 MB)
    int*     eb_dst = (int*)agg;             // 6.4 MB  (agg region: 25.6 MB)

    // ---- CSR build: two-level LDS-atomic counting sort (no global atomics) ----
    hist1_kernel<<<NBLK, 256, 0, stream>>>(dst, histM);
    gscan1_kernel<<<MHIST / 512, 512, 0, stream>>>(histM, incl, partials);
    gscan2_kernel<<<1, 512, 0, stream>>>(partials, chunk_off, MHIST / 512);
    gscan3_kernel<<<(MHIST + 255) / 256, 256, 0, stream>>>(histM, incl, chunk_off, ebase, bkt_ptr);
    scatter1_kernel<<<NBLK, 256, 0, stream>>>(src, dst, ea, ebase, eb_se, eb_dst);
    bucket_kernel<<<NBKT, 512, 0, stream>>>(bkt_ptr, eb_se, eb_dst, row_ptr, degw, epack);

    embed_kernel<<<(N_NODES * H + 255) / 256, 256, 0, stream>>>(x, Wemb, bemb, h);

    for (int l = 0; l < LAYERS; ++l) {
        linA_kernel<<<1024, 256, 0, stream>>>(
            h, pW1 + (size_t)l * H * H, pb1 + (size_t)l * H, a);
        linB_kernel<<<1024, 256, 0, stream>>>(
            h, degw, pW2 + (size_t)l * H * H,
            pW3 + (size_t)l * H * H, pb3 + (size_t)l * H, agg);
        gather_kernel<<<(N_NODES + 3) / 4, 256, 0, stream>>>(row_ptr, epack, a, agg, h);
    }

    poolhead_kernel<<<N_GRAPHS, 2 * H, 0, stream>>>(h, batch, Wf1, bf1v, Wf2, bf2v, out);
}

// Round 8
// 414.018 us; speedup vs baseline: 3.8141x; 1.1586x over previous
//
#include <hip/hip_runtime.h>

#define N_NODES 100000
#define N_EDGES 1600000
#define N_GRAPHS 512
#define X_DIM 4
#define H 64
#define LAYERS 3
#define NUM_CLASS 3
#define NBLK 256            // partition blocks
#define EPB (N_EDGES / NBLK)  // 6250 edges per partition block
#define BKT_BITS 9
#define BKT_SZ 512          // nodes per bucket
#define NBKT ((N_NODES + BKT_SZ - 1) / BKT_SZ)  // 196
#define MHIST (NBKT * NBLK)  // 50176, divisible by 512
#define LROW 72             // padded LDS row (shorts): 144 B = 16B-aligned per row
#define NCHUNKS ((N_NODES + 63) / 64)  // 1563

typedef unsigned short ushort;
typedef short bf16x8 __attribute__((ext_vector_type(8)));
typedef unsigned short ush8 __attribute__((ext_vector_type(8)));
typedef unsigned short ush4 __attribute__((ext_vector_type(4)));
typedef float floatx4 __attribute__((ext_vector_type(4)));

__device__ __forceinline__ ushort f2bf(float v) {
    unsigned u = __float_as_uint(v);
    unsigned r = (u + 0x7fff + ((u >> 16) & 1)) >> 16;  // round-nearest-even
    return (ushort)r;
}
__device__ __forceinline__ float bf2f(ushort s) {
    return __uint_as_float(((unsigned)s) << 16);
}

// ---------------- embed: h = bf16(x @ Wemb + bemb) ----------------
__global__ void embed_kernel(const float* __restrict__ x, const float* __restrict__ Wemb,
                             const float* __restrict__ bemb, ushort* __restrict__ h) {
    int i = blockIdx.x * blockDim.x + threadIdx.x;
    if (i >= N_NODES * H) return;
    int n = i >> 6, f = i & 63;
    float acc = bemb[f];
#pragma unroll
    for (int k = 0; k < X_DIM; ++k)
        acc += x[n * X_DIM + k] * Wemb[k * H + f];
    h[i] = f2bf(acc);
}

// ---------------- phase A: per-block bucket histogram (LDS atomics only) ----------------
__global__ __launch_bounds__(256) void hist1_kernel(const int* __restrict__ dst,
                                                    int* __restrict__ histM) {
    __shared__ int hist[NBKT];
    int t = threadIdx.x, b = blockIdx.x;
    for (int i = t; i < NBKT; i += 256) hist[i] = 0;
    __syncthreads();
    int e0 = b * EPB;
    for (int j = t; j < EPB; j += 256) {
        int d = dst[e0 + j];
        atomicAdd(hist + (d >> BKT_BITS), 1);
    }
    __syncthreads();
    for (int i = t; i < NBKT; i += 256) histM[i * NBLK + b] = hist[i];
}

// ---------------- generic scan over MHIST entries ----------------
__global__ __launch_bounds__(512) void gscan1_kernel(const int* __restrict__ v,
                                                     int* __restrict__ incl,
                                                     int* __restrict__ partials) {
    __shared__ int s[512];
    int tid = threadIdx.x;
    int i = blockIdx.x * 512 + tid;
    int x = (i < MHIST) ? v[i] : 0;
    s[tid] = x;
    for (int off = 1; off < 512; off <<= 1) {
        __syncthreads();
        int tv = (tid >= off) ? s[tid - off] : 0;
        __syncthreads();
        s[tid] += tv;
    }
    __syncthreads();
    if (i < MHIST) incl[i] = s[tid];
    if (tid == 511) partials[blockIdx.x] = s[tid];
}

__global__ __launch_bounds__(512) void gscan2_kernel(const int* __restrict__ partials,
                                                     int* __restrict__ chunk_off, int nchunk) {
    __shared__ int s[512];
    int tid = threadIdx.x;
    s[tid] = (tid < nchunk) ? partials[tid] : 0;
    for (int off = 1; off < 512; off <<= 1) {
        __syncthreads();
        int tv = (tid >= off) ? s[tid - off] : 0;
        __syncthreads();
        s[tid] += tv;
    }
    __syncthreads();
    int excl = (tid == 0) ? 0 : s[tid - 1];
    __syncthreads();
    if (tid < nchunk) chunk_off[tid] = excl;
}

__global__ void gscan3_kernel(const int* __restrict__ v, const int* __restrict__ incl,
                              const int* __restrict__ chunk_off,
                              int* __restrict__ ebase, int* __restrict__ bkt_ptr) {
    int i = blockIdx.x * 256 + threadIdx.x;
    if (i >= MHIST) return;
    int e = incl[i] + chunk_off[i >> 9] - v[i];
    ebase[i] = e;
    if ((i & (NBLK - 1)) == 0) bkt_ptr[i / NBLK] = e;
    if (i == MHIST - 1) bkt_ptr[NBKT] = e + v[i];
}

// ---------------- phase B: partition edges into bucket order (LDS cursors) ----------------
// packed edge word: src (17 bits) << 15 | bf16(ea) low 15 bits (sign always 0)
__global__ __launch_bounds__(256) void scatter1_kernel(
    const int* __restrict__ src, const int* __restrict__ dst, const float* __restrict__ ea,
    const int* __restrict__ ebase, unsigned* __restrict__ eb_se, int* __restrict__ eb_dst) {
    __shared__ int cur[NBKT];
    int t = threadIdx.x, b = blockIdx.x;
    for (int i = t; i < NBKT; i += 256) cur[i] = ebase[i * NBLK + b];
    __syncthreads();
    int e0 = b * EPB;
    for (int j = t; j < EPB; j += 256) {
        int e = e0 + j;
        int d = dst[e];
        int k = d >> BKT_BITS;
        int pos = atomicAdd(cur + k, 1);
        eb_se[pos] = ((unsigned)src[e] << 15) | (unsigned)f2bf(ea[e]);
        eb_dst[pos] = d;
    }
}

// ---------------- phase C: per-bucket CSR build + degw (LDS atomics only) ----------------
__global__ __launch_bounds__(512) void bucket_kernel(
    const int* __restrict__ bkt_ptr, const unsigned* __restrict__ eb_se,
    const int* __restrict__ eb_dst,
    int* __restrict__ row_ptr, float* __restrict__ degw, unsigned* __restrict__ epack) {
    __shared__ int cnt[BKT_SZ];
    __shared__ float dws[BKT_SZ];
    __shared__ int s[BKT_SZ];
    __shared__ int cur[BKT_SZ];
    int k = blockIdx.x, t = threadIdx.x;
    int base = k << BKT_BITS;
    int nn = N_NODES - base;
    if (nn > BKT_SZ) nn = BKT_SZ;
    cnt[t] = 0;
    dws[t] = 0.0f;
    __syncthreads();
    int beg = bkt_ptr[k], end = bkt_ptr[k + 1];
    for (int j = beg + t; j < end; j += 512) {
        int d = eb_dst[j] - base;
        atomicAdd(cnt + d, 1);
        atomicAdd(dws + d, __uint_as_float((eb_se[j] & 0x7FFFu) << 16));
    }
    __syncthreads();
    s[t] = cnt[t];
    for (int off = 1; off < 512; off <<= 1) {
        __syncthreads();
        int tv = (t >= off) ? s[t - off] : 0;
        __syncthreads();
        s[t] += tv;
    }
    __syncthreads();
    int rstart = beg + s[t] - cnt[t];
    if (t < nn) {
        row_ptr[base + t] = rstart;
        degw[base + t] = dws[t];
        cur[t] = rstart;
    }
    __syncthreads();
    for (int j = beg + t; j < end; j += 512) {
        unsigned se = eb_se[j];
        int d = eb_dst[j] - base;
        int pos = atomicAdd(cur + d, 1);
        epack[pos] = se;
    }
    if (k == NBKT - 1 && t == 0) row_ptr[N_NODES] = N_EDGES;
}

// ---------------- linAB: a = bf16(h@W1+b1); agg = h@W3+b3 - (h@W2)*degw ----------------
__global__ __launch_bounds__(256) void linAB_kernel(
    const ushort* __restrict__ h, const float* __restrict__ degw,
    const float* __restrict__ W1, const float* __restrict__ bias1,
    const float* __restrict__ W2, const float* __restrict__ W3,
    const float* __restrict__ bias3,
    ushort* __restrict__ a, float* __restrict__ agg) {
    __shared__ alignas(16) ushort w1hi[H * LROW];
    __shared__ alignas(16) ushort w1lo[H * LROW];
    __shared__ alignas(16) ushort w2hi[H * LROW];
    __shared__ alignas(16) ushort w2lo[H * LROW];
    __shared__ alignas(16) ushort w3hi[H * LROW];
    __shared__ alignas(16) ushort w3lo[H * LROW];
    __shared__ alignas(16) ushort ah[64 * LROW];   // total 64512 B
    int t = threadIdx.x;
    for (int i = t; i < H * H; i += 256) {
        int k = i >> 6, f = i & 63;
        float w1 = W1[i], w2 = W2[i], w3 = W3[i];
        ushort h1 = f2bf(w1), h2 = f2bf(w2), h3 = f2bf(w3);
        w1hi[f * LROW + k] = h1;
        w1lo[f * LROW + k] = f2bf(w1 - bf2f(h1));
        w2hi[f * LROW + k] = h2;
        w2lo[f * LROW + k] = f2bf(w2 - bf2f(h2));
        w3hi[f * LROW + k] = h3;
        w3lo[f * LROW + k] = f2bf(w3 - bf2f(h3));
    }
    int wv = t >> 6, lane = t & 63;
    int quad = lane >> 4, m16 = lane & 15;
    for (int chunk = blockIdx.x; chunk < NCHUNKS; chunk += gridDim.x) {
        int nbase = chunk * 64;
        __syncthreads();  // protect LDS reuse across iterations (and weight staging)
        for (int v = t; v < 64 * 8; v += 256) {   // 512 x 8-short vectors
            int nl = v >> 3, k0 = (v & 7) * 8;
            int n = nbase + nl;
            ush8 val = {0, 0, 0, 0, 0, 0, 0, 0};
            if (n < N_NODES) val = *(const ush8*)&h[(size_t)n * H + k0];
            *(ush8*)&ah[nl * LROW + k0] = val;
        }
        __syncthreads();
        int abase = (wv * 16 + m16) * LROW + quad * 8;
        bf16x8 Ah0 = *(const bf16x8*)&ah[abase];
        bf16x8 Ah1 = *(const bf16x8*)&ah[abase + 32];
        int nrow = nbase + wv * 16 + quad * 4;
        float dw[4];
#pragma unroll
        for (int r = 0; r < 4; ++r)
            dw[r] = (nrow + r < N_NODES) ? degw[nrow + r] : 0.0f;
#pragma unroll
        for (int tt = 0; tt < 4; ++tt) {
            floatx4 acc1 = {0.f, 0.f, 0.f, 0.f};
            floatx4 acc2 = {0.f, 0.f, 0.f, 0.f};
            floatx4 acc3 = {0.f, 0.f, 0.f, 0.f};
            int bbase = (tt * 16 + m16) * LROW + quad * 8;
            {
                bf16x8 B1h = *(const bf16x8*)&w1hi[bbase];
                bf16x8 B1l = *(const bf16x8*)&w1lo[bbase];
                acc1 = __builtin_amdgcn_mfma_f32_16x16x32_bf16(Ah0, B1h, acc1, 0, 0, 0);
                acc1 = __builtin_amdgcn_mfma_f32_16x16x32_bf16(Ah0, B1l, acc1, 0, 0, 0);
                bf16x8 B2h = *(const bf16x8*)&w2hi[bbase];
                bf16x8 B2l = *(const bf16x8*)&w2lo[bbase];
                acc2 = __builtin_amdgcn_mfma_f32_16x16x32_bf16(Ah0, B2h, acc2, 0, 0, 0);
                acc2 = __builtin_amdgcn_mfma_f32_16x16x32_bf16(Ah0, B2l, acc2, 0, 0, 0);
                bf16x8 B3h = *(const bf16x8*)&w3hi[bbase];
                bf16x8 B3l = *(const bf16x8*)&w3lo[bbase];
                acc3 = __builtin_amdgcn_mfma_f32_16x16x32_bf16(Ah0, B3h, acc3, 0, 0, 0);
                acc3 = __builtin_amdgcn_mfma_f32_16x16x32_bf16(Ah0, B3l, acc3, 0, 0, 0);
            }
            {
                bf16x8 B1h = *(const bf16x8*)&w1hi[bbase + 32];
                bf16x8 B1l = *(const bf16x8*)&w1lo[bbase + 32];
                acc1 = __builtin_amdgcn_mfma_f32_16x16x32_bf16(Ah1, B1h, acc1, 0, 0, 0);
                acc1 = __builtin_amdgcn_mfma_f32_16x16x32_bf16(Ah1, B1l, acc1, 0, 0, 0);
                bf16x8 B2h = *(const bf16x8*)&w2hi[bbase + 32];
                bf16x8 B2l = *(const bf16x8*)&w2lo[bbase + 32];
                acc2 = __builtin_amdgcn_mfma_f32_16x16x32_bf16(Ah1, B2h, acc2, 0, 0, 0);
                acc2 = __builtin_amdgcn_mfma_f32_16x16x32_bf16(Ah1, B2l, acc2, 0, 0, 0);
                bf16x8 B3h = *(const bf16x8*)&w3hi[bbase + 32];
                bf16x8 B3l = *(const bf16x8*)&w3lo[bbase + 32];
                acc3 = __builtin_amdgcn_mfma_f32_16x16x32_bf16(Ah1, B3h, acc3, 0, 0, 0);
                acc3 = __builtin_amdgcn_mfma_f32_16x16x32_bf16(Ah1, B3l, acc3, 0, 0, 0);
            }
            int f = tt * 16 + m16;
            float bb1 = bias1[f], bb3 = bias3[f];
#pragma unroll
            for (int r = 0; r < 4; ++r) {
                int n = nrow + r;
                if (n < N_NODES) {
                    a[(size_t)n * H + f] = f2bf(acc1[r] + bb1);
                    agg[(size_t)n * H + f] = acc3[r] + bb3 - acc2[r] * dw[r];
                }
            }
        }
    }
}

// ---------------- gather: h[d] = bf16(relu(agg_init[d] + sum_in ea*a[src])) ----------------
// wave = 1 node; lane = q*16+s: edge-slot q (0..3), feature quad s (features 4s..4s+3)
__global__ __launch_bounds__(256) void gather_kernel(
    const int* __restrict__ row_ptr, const unsigned* __restrict__ epack,
    const ushort* __restrict__ a, const float* __restrict__ agg_init,
    ushort* __restrict__ h) {
    int n = blockIdx.x * 4 + (threadIdx.x >> 6);
    if (n >= N_NODES) return;
    int lane = threadIdx.x & 63;
    int q = lane >> 4, s = lane & 15;
    int beg = row_ptr[n], end = row_ptr[n + 1];
    float acc0 = 0.f, acc1 = 0.f, acc2 = 0.f, acc3 = 0.f;
    for (int j = beg; j < end; j += 8) {
        int j0 = j + q, j1 = j + 4 + q;
        unsigned w0 = (j0 < end) ? epack[j0] : 0u;
        unsigned w1 = (j1 < end) ? epack[j1] : 0u;
        ush4 av0 = *(const ush4*)&a[(size_t)(w0 >> 15) * H + s * 4];
        ush4 av1 = *(const ush4*)&a[(size_t)(w1 >> 15) * H + s * 4];
        float e0 = __uint_as_float((w0 & 0x7FFFu) << 16);
        float e1 = __uint_as_float((w1 & 0x7FFFu) << 16);
        acc0 += e0 * bf2f(av0[0]) + e1 * bf2f(av1[0]);
        acc1 += e0 * bf2f(av0[1]) + e1 * bf2f(av1[1]);
        acc2 += e0 * bf2f(av0[2]) + e1 * bf2f(av1[2]);
        acc3 += e0 * bf2f(av0[3]) + e1 * bf2f(av1[3]);
    }
    // fold the 4 edge-slots: sum over q via xor-shuffles (16, 32)
    acc0 += __shfl_xor(acc0, 16); acc0 += __shfl_xor(acc0, 32);
    acc1 += __shfl_xor(acc1, 16); acc1 += __shfl_xor(acc1, 32);
    acc2 += __shfl_xor(acc2, 16); acc2 += __shfl_xor(acc2, 32);
    acc3 += __shfl_xor(acc3, 16); acc3 += __shfl_xor(acc3, 32);
    if (q == 0) {
        floatx4 ai = *(const floatx4*)&agg_init[(size_t)n * H + s * 4];
        ush4 r;
        r[0] = f2bf(fmaxf(acc0 + ai[0], 0.0f));
        r[1] = f2bf(fmaxf(acc1 + ai[1], 0.0f));
        r[2] = f2bf(fmaxf(acc2 + ai[2], 0.0f));
        r[3] = f2bf(fmaxf(acc3 + ai[3], 0.0f));
        *(ush4*)&h[(size_t)n * H + s * 4] = r;
    }
}

// ---------------- fused mean-pool + MLP head (batch is sorted) ----------------
__device__ __forceinline__ int lower_bound(const int* __restrict__ arr, int n, int key) {
    int lo = 0, hi = n;
    while (lo < hi) {
        int mid = (lo + hi) >> 1;
        if (arr[mid] < key) lo = mid + 1; else hi = mid;
    }
    return lo;
}

__global__ __launch_bounds__(128) void poolhead_kernel(
    const ushort* __restrict__ h, const int* __restrict__ batch,
    const float* __restrict__ Wf1, const float* __restrict__ bf1v,
    const float* __restrict__ Wf2, const float* __restrict__ bf2v,
    float* __restrict__ out) {
    __shared__ float psum[128];
    __shared__ float gx[H];
    __shared__ float hid[2 * H];
    int g = blockIdx.x, t = threadIdx.x;
    int s = lower_bound(batch, N_NODES, g);
    int e = lower_bound(batch, N_NODES, g + 1);
    int w = t >> 6, f = t & 63;
    float accf = 0.0f;
    for (int n = s + w; n < e; n += 2) accf += bf2f(h[(size_t)n * H + f]);
    psum[t] = accf;
    __syncthreads();
    if (t < H) {
        float c = (float)(e - s);
        gx[t] = (psum[t] + psum[t + 64]) / fmaxf(c, 1.0f);
    }
    __syncthreads();
    float acc = bf1v[t];
    for (int k = 0; k < H; ++k) acc += gx[k] * Wf1[k * 2 * H + t];
    hid[t] = fmaxf(acc, 0.0f);
    __syncthreads();
    if (t < NUM_CLASS) {
        float o = bf2v[t];
        for (int k = 0; k < 2 * H; ++k) o += hid[k] * Wf2[k * NUM_CLASS + t];
        out[g * NUM_CLASS + t] = o;
    }
}

extern "C" void kernel_launch(void* const* d_in, const int* in_sizes, int n_in,
                              void* d_out, int out_size, void* d_ws, size_t ws_size,
                              hipStream_t stream) {
    const float* x    = (const float*)d_in[0];
    const int*  ei    = (const int*)d_in[1];
    const int*  batch = (const int*)d_in[2];
    const float* ea   = (const float*)d_in[3];
    const float* Wemb = (const float*)d_in[4];
    const float* bemb = (const float*)d_in[5];
    const float* pW1  = (const float*)d_in[6];
    const float* pb1  = (const float*)d_in[7];
    const float* pW2  = (const float*)d_in[8];
    const float* pW3  = (const float*)d_in[9];
    const float* pb3  = (const float*)d_in[10];
    const float* Wf1  = (const float*)d_in[11];
    const float* bf1v = (const float*)d_in[12];
    const float* Wf2  = (const float*)d_in[13];
    const float* bf2v = (const float*)d_in[14];
    float* out = (float*)d_out;

    const int* src = ei;
    const int* dst = ei + N_EDGES;

    // ---- workspace layout ----
    const size_t NH = (size_t)N_NODES * H;
    char* p = (char*)d_ws;
    ushort* h       = (ushort*)p;            p += NH * 2;           // 12.8 MB
    ushort* a       = (ushort*)p;            p += NH * 2;           // 12.8 MB
    float*  agg     = (float*)p;             p += NH * 4;           // 25.6 MB
    unsigned* epack = (unsigned*)p;          p += (size_t)N_EDGES * 4;  // 6.4 MB
    int*   histM    = (int*)p;               p += MHIST * 4;
    int*   incl     = (int*)p;               p += MHIST * 4;
    int*   ebase    = (int*)p;               p += MHIST * 4;
    int*   partials = (int*)p;               p += 512 * 4;
    int*   chunk_off= (int*)p;               p += 512 * 4;
    int*   bkt_ptr  = (int*)p;               p += (NBKT + 1) * 4;
    int*   row_ptr  = (int*)p;               p += (N_NODES + 1) * 4;
    float* degw     = (float*)p;             p += N_NODES * 4;
    // staging overlays a/agg (dead until lin kernels; build completes first)
    unsigned* eb_se = (unsigned*)a;          // 6.4 MB  (a region: 12.8 MB)
    int*     eb_dst = (int*)agg;             // 6.4 MB  (agg region: 25.6 MB)

    // ---- CSR build: two-level LDS-atomic counting sort (no global atomics) ----
    hist1_kernel<<<NBLK, 256, 0, stream>>>(dst, histM);
    gscan1_kernel<<<MHIST / 512, 512, 0, stream>>>(histM, incl, partials);
    gscan2_kernel<<<1, 512, 0, stream>>>(partials, chunk_off, MHIST / 512);
    gscan3_kernel<<<(MHIST + 255) / 256, 256, 0, stream>>>(histM, incl, chunk_off, ebase, bkt_ptr);
    scatter1_kernel<<<NBLK, 256, 0, stream>>>(src, dst, ea, ebase, eb_se, eb_dst);
    bucket_kernel<<<NBKT, 512, 0, stream>>>(bkt_ptr, eb_se, eb_dst, row_ptr, degw, epack);

    embed_kernel<<<(N_NODES * H + 255) / 256, 256, 0, stream>>>(x, Wemb, bemb, h);

    for (int l = 0; l < LAYERS; ++l) {
        linAB_kernel<<<512, 256, 0, stream>>>(
            h, degw,
            pW1 + (size_t)l * H * H, pb1 + (size_t)l * H,
            pW2 + (size_t)l * H * H,
            pW3 + (size_t)l * H * H, pb3 + (size_t)l * H,
            a, agg);
        gather_kernel<<<(N_NODES + 3) / 4, 256, 0, stream>>>(row_ptr, epack, a, agg, h);
    }

    poolhead_kernel<<<N_GRAPHS, 2 * H, 0, stream>>>(h, batch, Wf1, bf1v, Wf2, bf2v, out);
}

// Round 9
// 371.366 us; speedup vs baseline: 4.2522x; 1.1149x over previous
//
#include <hip/hip_runtime.h>

#define N_NODES 100000
#define N_EDGES 1600000
#define N_GRAPHS 512
#define X_DIM 4
#define H 64
#define LAYERS 3
#define NUM_CLASS 3
#define NBLK 256            // partition blocks
#define EPB (N_EDGES / NBLK)  // 6250 edges per partition block
#define BKT_BITS 9
#define BKT_SZ 512          // nodes per bucket
#define NBKT ((N_NODES + BKT_SZ - 1) / BKT_SZ)  // 196
#define MHIST (NBKT * NBLK)  // 50176, divisible by 512
#define LROW 72             // padded LDS row (shorts): 144 B = 16B-aligned per row
#define NCHUNKS ((N_NODES + 63) / 64)  // 1563

typedef unsigned short ushort;
typedef short bf16x8 __attribute__((ext_vector_type(8)));
typedef unsigned short ush8 __attribute__((ext_vector_type(8)));
typedef float floatx4 __attribute__((ext_vector_type(4)));

__device__ __forceinline__ ushort f2bf(float v) {
    unsigned u = __float_as_uint(v);
    unsigned r = (u + 0x7fff + ((u >> 16) & 1)) >> 16;  // round-nearest-even
    return (ushort)r;
}
__device__ __forceinline__ float bf2f(ushort s) {
    return __uint_as_float(((unsigned)s) << 16);
}

// ---------------- embed: h = bf16(x @ Wemb + bemb) ----------------
__global__ void embed_kernel(const float* __restrict__ x, const float* __restrict__ Wemb,
                             const float* __restrict__ bemb, ushort* __restrict__ h) {
    int i = blockIdx.x * blockDim.x + threadIdx.x;
    if (i >= N_NODES * H) return;
    int n = i >> 6, f = i & 63;
    float acc = bemb[f];
#pragma unroll
    for (int k = 0; k < X_DIM; ++k)
        acc += x[n * X_DIM + k] * Wemb[k * H + f];
    h[i] = f2bf(acc);
}

// ---------------- phase A: per-block bucket histogram (LDS atomics only) ----------------
__global__ __launch_bounds__(256) void hist1_kernel(const int* __restrict__ dst,
                                                    int* __restrict__ histM) {
    __shared__ int hist[NBKT];
    int t = threadIdx.x, b = blockIdx.x;
    for (int i = t; i < NBKT; i += 256) hist[i] = 0;
    __syncthreads();
    int e0 = b * EPB;
    for (int j = t; j < EPB; j += 256) {
        int d = dst[e0 + j];
        atomicAdd(hist + (d >> BKT_BITS), 1);
    }
    __syncthreads();
    for (int i = t; i < NBKT; i += 256) histM[i * NBLK + b] = hist[i];
}

// ---------------- generic scan over MHIST entries ----------------
__global__ __launch_bounds__(512) void gscan1_kernel(const int* __restrict__ v,
                                                     int* __restrict__ incl,
                                                     int* __restrict__ partials) {
    __shared__ int s[512];
    int tid = threadIdx.x;
    int i = blockIdx.x * 512 + tid;
    int x = (i < MHIST) ? v[i] : 0;
    s[tid] = x;
    for (int off = 1; off < 512; off <<= 1) {
        __syncthreads();
        int tv = (tid >= off) ? s[tid - off] : 0;
        __syncthreads();
        s[tid] += tv;
    }
    __syncthreads();
    if (i < MHIST) incl[i] = s[tid];
    if (tid == 511) partials[blockIdx.x] = s[tid];
}

__global__ __launch_bounds__(512) void gscan2_kernel(const int* __restrict__ partials,
                                                     int* __restrict__ chunk_off, int nchunk) {
    __shared__ int s[512];
    int tid = threadIdx.x;
    s[tid] = (tid < nchunk) ? partials[tid] : 0;
    for (int off = 1; off < 512; off <<= 1) {
        __syncthreads();
        int tv = (tid >= off) ? s[tid - off] : 0;
        __syncthreads();
        s[tid] += tv;
    }
    __syncthreads();
    int excl = (tid == 0) ? 0 : s[tid - 1];
    __syncthreads();
    if (tid < nchunk) chunk_off[tid] = excl;
}

__global__ void gscan3_kernel(const int* __restrict__ v, const int* __restrict__ incl,
                              const int* __restrict__ chunk_off,
                              int* __restrict__ ebase, int* __restrict__ bkt_ptr) {
    int i = blockIdx.x * 256 + threadIdx.x;
    if (i >= MHIST) return;
    int e = incl[i] + chunk_off[i >> 9] - v[i];
    ebase[i] = e;
    if ((i & (NBLK - 1)) == 0) bkt_ptr[i / NBLK] = e;
    if (i == MHIST - 1) bkt_ptr[NBKT] = e + v[i];
}

// ---------------- phase B: partition edges into bucket order (LDS cursors) ----------------
// packed edge word: src (17 bits) << 15 | bf16(ea) low 15 bits (sign always 0)
__global__ __launch_bounds__(256) void scatter1_kernel(
    const int* __restrict__ src, const int* __restrict__ dst, const float* __restrict__ ea,
    const int* __restrict__ ebase, unsigned* __restrict__ eb_se, int* __restrict__ eb_dst) {
    __shared__ int cur[NBKT];
    int t = threadIdx.x, b = blockIdx.x;
    for (int i = t; i < NBKT; i += 256) cur[i] = ebase[i * NBLK + b];
    __syncthreads();
    int e0 = b * EPB;
    for (int j = t; j < EPB; j += 256) {
        int e = e0 + j;
        int d = dst[e];
        int k = d >> BKT_BITS;
        int pos = atomicAdd(cur + k, 1);
        eb_se[pos] = ((unsigned)src[e] << 15) | (unsigned)f2bf(ea[e]);
        eb_dst[pos] = d;
    }
}

// ---------------- phase C: per-bucket CSR build + degw (LDS atomics only) ----------------
__global__ __launch_bounds__(512) void bucket_kernel(
    const int* __restrict__ bkt_ptr, const unsigned* __restrict__ eb_se,
    const int* __restrict__ eb_dst,
    int* __restrict__ row_ptr, float* __restrict__ degw, unsigned* __restrict__ epack) {
    __shared__ int cnt[BKT_SZ];
    __shared__ float dws[BKT_SZ];
    __shared__ int s[BKT_SZ];
    __shared__ int cur[BKT_SZ];
    int k = blockIdx.x, t = threadIdx.x;
    int base = k << BKT_BITS;
    int nn = N_NODES - base;
    if (nn > BKT_SZ) nn = BKT_SZ;
    cnt[t] = 0;
    dws[t] = 0.0f;
    __syncthreads();
    int beg = bkt_ptr[k], end = bkt_ptr[k + 1];
    for (int j = beg + t; j < end; j += 512) {
        int d = eb_dst[j] - base;
        atomicAdd(cnt + d, 1);
        atomicAdd(dws + d, __uint_as_float((eb_se[j] & 0x7FFFu) << 16));
    }
    __syncthreads();
    s[t] = cnt[t];
    for (int off = 1; off < 512; off <<= 1) {
        __syncthreads();
        int tv = (t >= off) ? s[t - off] : 0;
        __syncthreads();
        s[t] += tv;
    }
    __syncthreads();
    int rstart = beg + s[t] - cnt[t];
    if (t < nn) {
        row_ptr[base + t] = rstart;
        degw[base + t] = dws[t];
        cur[t] = rstart;
    }
    __syncthreads();
    for (int j = beg + t; j < end; j += 512) {
        unsigned se = eb_se[j];
        int d = eb_dst[j] - base;
        int pos = atomicAdd(cur + d, 1);
        epack[pos] = se;
    }
    if (k == NBKT - 1 && t == 0) row_ptr[N_NODES] = N_EDGES;
}

// ---------------- linAB: a = bf16(h@W1+b1); aggb = bf16(h@W3+b3 - (h@W2)*degw) ----------------
// B-fragments resident in registers (chunk-invariant); LDS only stages the A (h) tile.
// wave wv handles feature tile f = wv*16 + m16 for all 64 nodes of the chunk.
__global__ __launch_bounds__(256) void linAB_kernel(
    const ushort* __restrict__ h, const float* __restrict__ degw,
    const float* __restrict__ W1, const float* __restrict__ bias1,
    const float* __restrict__ W2, const float* __restrict__ W3,
    const float* __restrict__ bias3,
    ushort* __restrict__ a, ushort* __restrict__ aggb) {
    __shared__ alignas(16) ushort ah[64 * LROW];  // 18432 B
    int t = threadIdx.x;
    int wv = t >> 6, lane = t & 63;
    int quad = lane >> 4, m16 = lane & 15;
    int f = wv * 16 + m16;
    // load B-frags: [weight][khalf][hi/lo]; frag element j = W[(kh*32+quad*8+j)*H + f]
    bf16x8 B[3][2][2];
    const float* Ws[3] = {W1, W2, W3};
#pragma unroll
    for (int wsel = 0; wsel < 3; ++wsel) {
#pragma unroll
        for (int kh = 0; kh < 2; ++kh) {
#pragma unroll
            for (int j = 0; j < 8; ++j) {
                float w = Ws[wsel][(kh * 32 + quad * 8 + j) * H + f];
                ushort hi = f2bf(w);
                B[wsel][kh][0][j] = (short)hi;
                B[wsel][kh][1][j] = (short)f2bf(w - bf2f(hi));
            }
        }
    }
    float bb1 = bias1[f], bb3 = bias3[f];
    int nbase = blockIdx.x * 64;
    for (int v = t; v < 64 * 8; v += 256) {   // 512 x 8-short vectors
        int nl = v >> 3, k0 = (v & 7) * 8;
        int n = nbase + nl;
        ush8 val = {0, 0, 0, 0, 0, 0, 0, 0};
        if (n < N_NODES) val = *(const ush8*)&h[(size_t)n * H + k0];
        *(ush8*)&ah[nl * LROW + k0] = val;
    }
    __syncthreads();
#pragma unroll
    for (int ng = 0; ng < 4; ++ng) {
        int abase = (ng * 16 + m16) * LROW + quad * 8;
        bf16x8 A0 = *(const bf16x8*)&ah[abase];
        bf16x8 A1 = *(const bf16x8*)&ah[abase + 32];
        floatx4 acc1 = {0.f, 0.f, 0.f, 0.f};
        floatx4 acc2 = {0.f, 0.f, 0.f, 0.f};
        floatx4 acc3 = {0.f, 0.f, 0.f, 0.f};
        acc1 = __builtin_amdgcn_mfma_f32_16x16x32_bf16(A0, B[0][0][0], acc1, 0, 0, 0);
        acc1 = __builtin_amdgcn_mfma_f32_16x16x32_bf16(A0, B[0][0][1], acc1, 0, 0, 0);
        acc1 = __builtin_amdgcn_mfma_f32_16x16x32_bf16(A1, B[0][1][0], acc1, 0, 0, 0);
        acc1 = __builtin_amdgcn_mfma_f32_16x16x32_bf16(A1, B[0][1][1], acc1, 0, 0, 0);
        acc2 = __builtin_amdgcn_mfma_f32_16x16x32_bf16(A0, B[1][0][0], acc2, 0, 0, 0);
        acc2 = __builtin_amdgcn_mfma_f32_16x16x32_bf16(A0, B[1][0][1], acc2, 0, 0, 0);
        acc2 = __builtin_amdgcn_mfma_f32_16x16x32_bf16(A1, B[1][1][0], acc2, 0, 0, 0);
        acc2 = __builtin_amdgcn_mfma_f32_16x16x32_bf16(A1, B[1][1][1], acc2, 0, 0, 0);
        acc3 = __builtin_amdgcn_mfma_f32_16x16x32_bf16(A0, B[2][0][0], acc3, 0, 0, 0);
        acc3 = __builtin_amdgcn_mfma_f32_16x16x32_bf16(A0, B[2][0][1], acc3, 0, 0, 0);
        acc3 = __builtin_amdgcn_mfma_f32_16x16x32_bf16(A1, B[2][1][0], acc3, 0, 0, 0);
        acc3 = __builtin_amdgcn_mfma_f32_16x16x32_bf16(A1, B[2][1][1], acc3, 0, 0, 0);
        int nrow = nbase + ng * 16 + quad * 4;
#pragma unroll
        for (int r = 0; r < 4; ++r) {
            int n = nrow + r;
            if (n < N_NODES) {
                float dw = degw[n];
                a[(size_t)n * H + f] = f2bf(acc1[r] + bb1);
                aggb[(size_t)n * H + f] = f2bf(acc3[r] + bb3 - acc2[r] * dw);
            }
        }
    }
}

// ---------------- gather: h[d] = bf16(relu(aggb[d] + sum_in ea*a[src])) ----------------
// wave = 1 node; lane = q*8+s: edge-slot q (0..7), feature octet s (features 8s..8s+7)
// k-unroll 4 -> 32 edges of loads in flight in ONE dependency round (covers deg<=32)
__global__ __launch_bounds__(256) void gather_kernel(
    const int* __restrict__ row_ptr, const unsigned* __restrict__ epack,
    const ushort* __restrict__ a, const ushort* __restrict__ aggb,
    ushort* __restrict__ h) {
    int n = blockIdx.x * 4 + (threadIdx.x >> 6);
    if (n >= N_NODES) return;
    int lane = threadIdx.x & 63;
    int q = lane >> 3, s = lane & 7;
    int beg = row_ptr[n], end = row_ptr[n + 1];
    float acc[8] = {0.f, 0.f, 0.f, 0.f, 0.f, 0.f, 0.f, 0.f};
    for (int j = beg; j < end; j += 32) {
        unsigned w[4];
#pragma unroll
        for (int k = 0; k < 4; ++k) {
            int jk = j + k * 8 + q;
            w[k] = (jk < end) ? epack[jk] : 0u;
        }
        ush8 av[4];
#pragma unroll
        for (int k = 0; k < 4; ++k)
            av[k] = *(const ush8*)&a[(size_t)(w[k] >> 15) * H + s * 8];
#pragma unroll
        for (int k = 0; k < 4; ++k) {
            float e = __uint_as_float((w[k] & 0x7FFFu) << 16);
#pragma unroll
            for (int i = 0; i < 8; ++i)
                acc[i] += e * bf2f((ushort)av[k][i]);
        }
    }
#pragma unroll
    for (int i = 0; i < 8; ++i) {
        acc[i] += __shfl_xor(acc[i], 8);
        acc[i] += __shfl_xor(acc[i], 16);
        acc[i] += __shfl_xor(acc[i], 32);
    }
    if (q == 0) {
        ush8 ag = *(const ush8*)&aggb[(size_t)n * H + s * 8];
        ush8 r;
#pragma unroll
        for (int i = 0; i < 8; ++i)
            r[i] = (short)f2bf(fmaxf(acc[i] + bf2f((ushort)ag[i]), 0.0f));
        *(ush8*)&h[(size_t)n * H + s * 8] = r;
    }
}

// ---------------- fused mean-pool + MLP head (batch is sorted) ----------------
__device__ __forceinline__ int lower_bound(const int* __restrict__ arr, int n, int key) {
    int lo = 0, hi = n;
    while (lo < hi) {
        int mid = (lo + hi) >> 1;
        if (arr[mid] < key) lo = mid + 1; else hi = mid;
    }
    return lo;
}

__global__ __launch_bounds__(128) void poolhead_kernel(
    const ushort* __restrict__ h, const int* __restrict__ batch,
    const float* __restrict__ Wf1, const float* __restrict__ bf1v,
    const float* __restrict__ Wf2, const float* __restrict__ bf2v,
    float* __restrict__ out) {
    __shared__ float psum[128];
    __shared__ float gx[H];
    __shared__ float hid[2 * H];
    int g = blockIdx.x, t = threadIdx.x;
    int s = lower_bound(batch, N_NODES, g);
    int e = lower_bound(batch, N_NODES, g + 1);
    int w = t >> 6, f = t & 63;
    float accf = 0.0f;
    for (int n = s + w; n < e; n += 2) accf += bf2f(h[(size_t)n * H + f]);
    psum[t] = accf;
    __syncthreads();
    if (t < H) {
        float c = (float)(e - s);
        gx[t] = (psum[t] + psum[t + 64]) / fmaxf(c, 1.0f);
    }
    __syncthreads();
    float acc = bf1v[t];
    for (int k = 0; k < H; ++k) acc += gx[k] * Wf1[k * 2 * H + t];
    hid[t] = fmaxf(acc, 0.0f);
    __syncthreads();
    if (t < NUM_CLASS) {
        float o = bf2v[t];
        for (int k = 0; k < 2 * H; ++k) o += hid[k] * Wf2[k * NUM_CLASS + t];
        out[g * NUM_CLASS + t] = o;
    }
}

extern "C" void kernel_launch(void* const* d_in, const int* in_sizes, int n_in,
                              void* d_out, int out_size, void* d_ws, size_t ws_size,
                              hipStream_t stream) {
    const float* x    = (const float*)d_in[0];
    const int*  ei    = (const int*)d_in[1];
    const int*  batch = (const int*)d_in[2];
    const float* ea   = (const float*)d_in[3];
    const float* Wemb = (const float*)d_in[4];
    const float* bemb = (const float*)d_in[5];
    const float* pW1  = (const float*)d_in[6];
    const float* pb1  = (const float*)d_in[7];
    const float* pW2  = (const float*)d_in[8];
    const float* pW3  = (const float*)d_in[9];
    const float* pb3  = (const float*)d_in[10];
    const float* Wf1  = (const float*)d_in[11];
    const float* bf1v = (const float*)d_in[12];
    const float* Wf2  = (const float*)d_in[13];
    const float* bf2v = (const float*)d_in[14];
    float* out = (float*)d_out;

    const int* src = ei;
    const int* dst = ei + N_EDGES;

    // ---- workspace layout ----
    const size_t NH = (size_t)N_NODES * H;
    char* p = (char*)d_ws;
    ushort* h       = (ushort*)p;            p += NH * 2;           // 12.8 MB
    ushort* a       = (ushort*)p;            p += NH * 2;           // 12.8 MB
    ushort* aggb    = (ushort*)p;            p += NH * 2;           // 12.8 MB
    unsigned* epack = (unsigned*)p;          p += (size_t)N_EDGES * 4;  // 6.4 MB
    int*   histM    = (int*)p;               p += MHIST * 4;
    int*   incl     = (int*)p;               p += MHIST * 4;
    int*   ebase    = (int*)p;               p += MHIST * 4;
    int*   partials = (int*)p;               p += 512 * 4;
    int*   chunk_off= (int*)p;               p += 512 * 4;
    int*   bkt_ptr  = (int*)p;               p += (NBKT + 1) * 4;
    int*   row_ptr  = (int*)p;               p += (N_NODES + 1) * 4;
    float* degw     = (float*)p;             p += N_NODES * 4;
    // staging overlays a/aggb (dead until lin kernels; build completes first)
    unsigned* eb_se = (unsigned*)a;          // 6.4 MB  (a region: 12.8 MB)
    int*     eb_dst = (int*)aggb;            // 6.4 MB  (aggb region: 12.8 MB)

    // ---- CSR build: two-level LDS-atomic counting sort (no global atomics) ----
    hist1_kernel<<<NBLK, 256, 0, stream>>>(dst, histM);
    gscan1_kernel<<<MHIST / 512, 512, 0, stream>>>(histM, incl, partials);
    gscan2_kernel<<<1, 512, 0, stream>>>(partials, chunk_off, MHIST / 512);
    gscan3_kernel<<<(MHIST + 255) / 256, 256, 0, stream>>>(histM, incl, chunk_off, ebase, bkt_ptr);
    scatter1_kernel<<<NBLK, 256, 0, stream>>>(src, dst, ea, ebase, eb_se, eb_dst);
    bucket_kernel<<<NBKT, 512, 0, stream>>>(bkt_ptr, eb_se, eb_dst, row_ptr, degw, epack);

    embed_kernel<<<(N_NODES * H + 255) / 256, 256, 0, stream>>>(x, Wemb, bemb, h);

    for (int l = 0; l < LAYERS; ++l) {
        linAB_kernel<<<NCHUNKS, 256, 0, stream>>>(
            h, degw,
            pW1 + (size_t)l * H * H, pb1 + (size_t)l * H,
            pW2 + (size_t)l * H * H,
            pW3 + (size_t)l * H * H, pb3 + (size_t)l * H,
            a, aggb);
        gather_kernel<<<(N_NODES + 3) / 4, 256, 0, stream>>>(row_ptr, epack, a, aggb, h);
    }

    poolhead_kernel<<<N_GRAPHS, 2 * H, 0, stream>>>(h, batch, Wf1, bf1v, Wf2, bf2v, out);
}

// Round 10
// 358.095 us; speedup vs baseline: 4.4098x; 1.0371x over previous
//
#include <hip/hip_runtime.h>

#define N_NODES 100000
#define N_EDGES 1600000
#define N_GRAPHS 512
#define X_DIM 4
#define H 64
#define LAYERS 3
#define NUM_CLASS 3
#define NBLK 256            // partition blocks
#define EPB (N_EDGES / NBLK)  // 6250 edges per partition block
#define BKT_BITS 9
#define BKT_SZ 512          // nodes per bucket
#define NBKT ((N_NODES + BKT_SZ - 1) / BKT_SZ)  // 196
#define MHIST (NBKT * NBLK)  // 50176, divisible by 512
#define LROW 72             // padded LDS row (shorts): 144 B = 16B-aligned per row
#define NCHUNKS ((N_NODES + 63) / 64)  // 1563

typedef unsigned short ushort;
typedef short bf16x8 __attribute__((ext_vector_type(8)));
typedef unsigned short ush8 __attribute__((ext_vector_type(8)));
typedef float floatx4 __attribute__((ext_vector_type(4)));

__device__ __forceinline__ ushort f2bf(float v) {
    unsigned u = __float_as_uint(v);
    unsigned r = (u + 0x7fff + ((u >> 16) & 1)) >> 16;  // round-nearest-even
    return (ushort)r;
}
__device__ __forceinline__ float bf2f(ushort s) {
    return __uint_as_float(((unsigned)s) << 16);
}

// ---------------- embed: h = bf16(x @ Wemb + bemb) ----------------
__global__ void embed_kernel(const float* __restrict__ x, const float* __restrict__ Wemb,
                             const float* __restrict__ bemb, ushort* __restrict__ h) {
    int i = blockIdx.x * blockDim.x + threadIdx.x;
    if (i >= N_NODES * H) return;
    int n = i >> 6, f = i & 63;
    float acc = bemb[f];
#pragma unroll
    for (int k = 0; k < X_DIM; ++k)
        acc += x[n * X_DIM + k] * Wemb[k * H + f];
    h[i] = f2bf(acc);
}

// ---------------- phase A: per-block bucket histogram (LDS atomics only) ----------------
__global__ __launch_bounds__(256) void hist1_kernel(const int* __restrict__ dst,
                                                    int* __restrict__ histM) {
    __shared__ int hist[NBKT];
    int t = threadIdx.x, b = blockIdx.x;
    for (int i = t; i < NBKT; i += 256) hist[i] = 0;
    __syncthreads();
    int e0 = b * EPB;
    for (int j = t; j < EPB; j += 256) {
        int d = dst[e0 + j];
        atomicAdd(hist + (d >> BKT_BITS), 1);
    }
    __syncthreads();
    for (int i = t; i < NBKT; i += 256) histM[i * NBLK + b] = hist[i];
}

// ---------------- generic scan over MHIST entries ----------------
__global__ __launch_bounds__(512) void gscan1_kernel(const int* __restrict__ v,
                                                     int* __restrict__ incl,
                                                     int* __restrict__ partials) {
    __shared__ int s[512];
    int tid = threadIdx.x;
    int i = blockIdx.x * 512 + tid;
    int x = (i < MHIST) ? v[i] : 0;
    s[tid] = x;
    for (int off = 1; off < 512; off <<= 1) {
        __syncthreads();
        int tv = (tid >= off) ? s[tid - off] : 0;
        __syncthreads();
        s[tid] += tv;
    }
    __syncthreads();
    if (i < MHIST) incl[i] = s[tid];
    if (tid == 511) partials[blockIdx.x] = s[tid];
}

__global__ __launch_bounds__(512) void gscan2_kernel(const int* __restrict__ partials,
                                                     int* __restrict__ chunk_off, int nchunk) {
    __shared__ int s[512];
    int tid = threadIdx.x;
    s[tid] = (tid < nchunk) ? partials[tid] : 0;
    for (int off = 1; off < 512; off <<= 1) {
        __syncthreads();
        int tv = (tid >= off) ? s[tid - off] : 0;
        __syncthreads();
        s[tid] += tv;
    }
    __syncthreads();
    int excl = (tid == 0) ? 0 : s[tid - 1];
    __syncthreads();
    if (tid < nchunk) chunk_off[tid] = excl;
}

__global__ void gscan3_kernel(const int* __restrict__ v, const int* __restrict__ incl,
                              const int* __restrict__ chunk_off,
                              int* __restrict__ ebase, int* __restrict__ bkt_ptr) {
    int i = blockIdx.x * 256 + threadIdx.x;
    if (i >= MHIST) return;
    int e = incl[i] + chunk_off[i >> 9] - v[i];
    ebase[i] = e;
    if ((i & (NBLK - 1)) == 0) bkt_ptr[i / NBLK] = e;
    if (i == MHIST - 1) bkt_ptr[NBKT] = e + v[i];
}

// ---------------- phase B: partition edges into bucket order (LDS cursors) ----------------
// packed edge word: src (17 bits) << 15 | bf16(ea) low 15 bits (sign always 0)
__global__ __launch_bounds__(256) void scatter1_kernel(
    const int* __restrict__ src, const int* __restrict__ dst, const float* __restrict__ ea,
    const int* __restrict__ ebase, unsigned* __restrict__ eb_se, int* __restrict__ eb_dst) {
    __shared__ int cur[NBKT];
    int t = threadIdx.x, b = blockIdx.x;
    for (int i = t; i < NBKT; i += 256) cur[i] = ebase[i * NBLK + b];
    __syncthreads();
    int e0 = b * EPB;
    for (int j = t; j < EPB; j += 256) {
        int e = e0 + j;
        int d = dst[e];
        int k = d >> BKT_BITS;
        int pos = atomicAdd(cur + k, 1);
        eb_se[pos] = ((unsigned)src[e] << 15) | (unsigned)f2bf(ea[e]);
        eb_dst[pos] = d;
    }
}

// ---------------- phase C: per-bucket CSR build + degw (LDS atomics only) ----------------
__global__ __launch_bounds__(512) void bucket_kernel(
    const int* __restrict__ bkt_ptr, const unsigned* __restrict__ eb_se,
    const int* __restrict__ eb_dst,
    int* __restrict__ row_ptr, float* __restrict__ degw, unsigned* __restrict__ epack) {
    __shared__ int cnt[BKT_SZ];
    __shared__ float dws[BKT_SZ];
    __shared__ int s[BKT_SZ];
    __shared__ int cur[BKT_SZ];
    int k = blockIdx.x, t = threadIdx.x;
    int base = k << BKT_BITS;
    int nn = N_NODES - base;
    if (nn > BKT_SZ) nn = BKT_SZ;
    cnt[t] = 0;
    dws[t] = 0.0f;
    __syncthreads();
    int beg = bkt_ptr[k], end = bkt_ptr[k + 1];
    for (int j = beg + t; j < end; j += 512) {
        int d = eb_dst[j] - base;
        atomicAdd(cnt + d, 1);
        atomicAdd(dws + d, __uint_as_float((eb_se[j] & 0x7FFFu) << 16));
    }
    __syncthreads();
    s[t] = cnt[t];
    for (int off = 1; off < 512; off <<= 1) {
        __syncthreads();
        int tv = (t >= off) ? s[t - off] : 0;
        __syncthreads();
        s[t] += tv;
    }
    __syncthreads();
    int rstart = beg + s[t] - cnt[t];
    if (t < nn) {
        row_ptr[base + t] = rstart;
        degw[base + t] = dws[t];
        cur[t] = rstart;
    }
    __syncthreads();
    for (int j = beg + t; j < end; j += 512) {
        unsigned se = eb_se[j];
        int d = eb_dst[j] - base;
        int pos = atomicAdd(cur + d, 1);
        epack[pos] = se;
    }
    if (k == NBKT - 1 && t == 0) row_ptr[N_NODES] = N_EDGES;
}

// ---------------- linAB: a = bf16(h@W1+b1); aggb = bf16(h@W3+b3 - (h@W2)*degw) ----------------
// Persistent blocks; B-fragments loaded into registers ONCE per block.
__global__ __launch_bounds__(256) void linAB_kernel(
    const ushort* __restrict__ h, const float* __restrict__ degw,
    const float* __restrict__ W1, const float* __restrict__ bias1,
    const float* __restrict__ W2, const float* __restrict__ W3,
    const float* __restrict__ bias3,
    ushort* __restrict__ a, ushort* __restrict__ aggb) {
    __shared__ alignas(16) ushort ah[64 * LROW];  // 18432 B
    int t = threadIdx.x;
    int wv = t >> 6, lane = t & 63;
    int quad = lane >> 4, m16 = lane & 15;
    int f = wv * 16 + m16;
    // load B-frags: [weight][khalf][hi/lo]; frag element j = W[(kh*32+quad*8+j)*H + f]
    bf16x8 B[3][2][2];
    const float* Ws[3] = {W1, W2, W3};
#pragma unroll
    for (int wsel = 0; wsel < 3; ++wsel) {
#pragma unroll
        for (int kh = 0; kh < 2; ++kh) {
#pragma unroll
            for (int j = 0; j < 8; ++j) {
                float w = Ws[wsel][(kh * 32 + quad * 8 + j) * H + f];
                ushort hi = f2bf(w);
                B[wsel][kh][0][j] = (short)hi;
                B[wsel][kh][1][j] = (short)f2bf(w - bf2f(hi));
            }
        }
    }
    float bb1 = bias1[f], bb3 = bias3[f];
    for (int chunk = blockIdx.x; chunk < NCHUNKS; chunk += gridDim.x) {
        int nbase = chunk * 64;
        __syncthreads();  // protect LDS reuse across chunk iterations
        for (int v = t; v < 64 * 8; v += 256) {   // 512 x 8-short vectors
            int nl = v >> 3, k0 = (v & 7) * 8;
            int n = nbase + nl;
            ush8 val = {0, 0, 0, 0, 0, 0, 0, 0};
            if (n < N_NODES) val = *(const ush8*)&h[(size_t)n * H + k0];
            *(ush8*)&ah[nl * LROW + k0] = val;
        }
        __syncthreads();
#pragma unroll
        for (int ng = 0; ng < 4; ++ng) {
            int abase = (ng * 16 + m16) * LROW + quad * 8;
            bf16x8 A0 = *(const bf16x8*)&ah[abase];
            bf16x8 A1 = *(const bf16x8*)&ah[abase + 32];
            floatx4 acc1 = {0.f, 0.f, 0.f, 0.f};
            floatx4 acc2 = {0.f, 0.f, 0.f, 0.f};
            floatx4 acc3 = {0.f, 0.f, 0.f, 0.f};
            acc1 = __builtin_amdgcn_mfma_f32_16x16x32_bf16(A0, B[0][0][0], acc1, 0, 0, 0);
            acc1 = __builtin_amdgcn_mfma_f32_16x16x32_bf16(A0, B[0][0][1], acc1, 0, 0, 0);
            acc1 = __builtin_amdgcn_mfma_f32_16x16x32_bf16(A1, B[0][1][0], acc1, 0, 0, 0);
            acc1 = __builtin_amdgcn_mfma_f32_16x16x32_bf16(A1, B[0][1][1], acc1, 0, 0, 0);
            acc2 = __builtin_amdgcn_mfma_f32_16x16x32_bf16(A0, B[1][0][0], acc2, 0, 0, 0);
            acc2 = __builtin_amdgcn_mfma_f32_16x16x32_bf16(A0, B[1][0][1], acc2, 0, 0, 0);
            acc2 = __builtin_amdgcn_mfma_f32_16x16x32_bf16(A1, B[1][1][0], acc2, 0, 0, 0);
            acc2 = __builtin_amdgcn_mfma_f32_16x16x32_bf16(A1, B[1][1][1], acc2, 0, 0, 0);
            acc3 = __builtin_amdgcn_mfma_f32_16x16x32_bf16(A0, B[2][0][0], acc3, 0, 0, 0);
            acc3 = __builtin_amdgcn_mfma_f32_16x16x32_bf16(A0, B[2][0][1], acc3, 0, 0, 0);
            acc3 = __builtin_amdgcn_mfma_f32_16x16x32_bf16(A1, B[2][1][0], acc3, 0, 0, 0);
            acc3 = __builtin_amdgcn_mfma_f32_16x16x32_bf16(A1, B[2][1][1], acc3, 0, 0, 0);
            int nrow = nbase + ng * 16 + quad * 4;
#pragma unroll
            for (int r = 0; r < 4; ++r) {
                int n = nrow + r;
                if (n < N_NODES) {
                    float dw = degw[n];
                    a[(size_t)n * H + f] = f2bf(acc1[r] + bb1);
                    aggb[(size_t)n * H + f] = f2bf(acc3[r] + bb3 - acc2[r] * dw);
                }
            }
        }
    }
}

// ---------------- gather: h[d] = bf16(relu(aggb[d] + sum_in ea*a[src])) ----------------
// wave = 1 node; lane = q*8+s: edge-slot q (0..7), feature octet s (features 8s..8s+7)
// k-unroll 4 -> 32 edges of loads in flight in ONE dependency round (covers deg<=32)
__global__ __launch_bounds__(256) void gather_kernel(
    const int* __restrict__ row_ptr, const unsigned* __restrict__ epack,
    const ushort* __restrict__ a, const ushort* __restrict__ aggb,
    ushort* __restrict__ h) {
    int n = blockIdx.x * 4 + (threadIdx.x >> 6);
    if (n >= N_NODES) return;
    int lane = threadIdx.x & 63;
    int q = lane >> 3, s = lane & 7;
    int beg = row_ptr[n], end = row_ptr[n + 1];
    float acc[8] = {0.f, 0.f, 0.f, 0.f, 0.f, 0.f, 0.f, 0.f};
    for (int j = beg; j < end; j += 32) {
        unsigned w[4];
#pragma unroll
        for (int k = 0; k < 4; ++k) {
            int jk = j + k * 8 + q;
            w[k] = (jk < end) ? epack[jk] : 0u;
        }
        ush8 av[4];
#pragma unroll
        for (int k = 0; k < 4; ++k)
            av[k] = *(const ush8*)&a[(size_t)(w[k] >> 15) * H + s * 8];
#pragma unroll
        for (int k = 0; k < 4; ++k) {
            float e = __uint_as_float((w[k] & 0x7FFFu) << 16);
#pragma unroll
            for (int i = 0; i < 8; ++i)
                acc[i] += e * bf2f((ushort)av[k][i]);
        }
    }
#pragma unroll
    for (int i = 0; i < 8; ++i) {
        acc[i] += __shfl_xor(acc[i], 8);
        acc[i] += __shfl_xor(acc[i], 16);
        acc[i] += __shfl_xor(acc[i], 32);
    }
    if (q == 0) {
        ush8 ag = *(const ush8*)&aggb[(size_t)n * H + s * 8];
        ush8 r;
#pragma unroll
        for (int i = 0; i < 8; ++i)
            r[i] = (short)f2bf(fmaxf(acc[i] + bf2f((ushort)ag[i]), 0.0f));
        *(ush8*)&h[(size_t)n * H + s * 8] = r;
    }
}

// ---------------- fused mean-pool + MLP head (batch is sorted) ----------------
__device__ __forceinline__ int lower_bound(const int* __restrict__ arr, int n, int key) {
    int lo = 0, hi = n;
    while (lo < hi) {
        int mid = (lo + hi) >> 1;
        if (arr[mid] < key) lo = mid + 1; else hi = mid;
    }
    return lo;
}

// 256 threads: lane = slot*8 + octet; wave covers 8 nodes x 128 B contiguous per inst
__global__ __launch_bounds__(256) void poolhead_kernel(
    const ushort* __restrict__ h, const int* __restrict__ batch,
    const float* __restrict__ Wf1, const float* __restrict__ bf1v,
    const float* __restrict__ Wf2, const float* __restrict__ bf2v,
    float* __restrict__ out) {
    __shared__ float psum[4][H];
    __shared__ float gx[H];
    __shared__ float hid[2 * H];
    int g = blockIdx.x, t = threadIdx.x;
    int s = lower_bound(batch, N_NODES, g);
    int e = lower_bound(batch, N_NODES, g + 1);
    int lane = t & 63, wv = t >> 6;
    int o = lane & 7;       // feature octet: features 8o..8o+7
    int nd = t >> 3;        // node slot 0..31 (8 per wave x 4 waves)
    float acc[8] = {0.f, 0.f, 0.f, 0.f, 0.f, 0.f, 0.f, 0.f};
    for (int n = s + nd; n < e; n += 32) {
        ush8 v = *(const ush8*)&h[(size_t)n * H + o * 8];
#pragma unroll
        for (int i = 0; i < 8; ++i) acc[i] += bf2f((ushort)v[i]);
    }
#pragma unroll
    for (int i = 0; i < 8; ++i) {
        acc[i] += __shfl_xor(acc[i], 8);
        acc[i] += __shfl_xor(acc[i], 16);
        acc[i] += __shfl_xor(acc[i], 32);
    }
    if (lane < 8) {
#pragma unroll
        for (int i = 0; i < 8; ++i) psum[wv][o * 8 + i] = acc[i];
    }
    __syncthreads();
    if (t < H) {
        float c = (float)(e - s);
        gx[t] = (psum[0][t] + psum[1][t] + psum[2][t] + psum[3][t]) / fmaxf(c, 1.0f);
    }
    __syncthreads();
    if (t < 2 * H) {
        float acc2 = bf1v[t];
        for (int k = 0; k < H; ++k) acc2 += gx[k] * Wf1[k * 2 * H + t];
        hid[t] = fmaxf(acc2, 0.0f);
    }
    __syncthreads();
    if (t < NUM_CLASS) {
        float o2 = bf2v[t];
        for (int k = 0; k < 2 * H; ++k) o2 += hid[k] * Wf2[k * NUM_CLASS + t];
        out[g * NUM_CLASS + t] = o2;
    }
}

extern "C" void kernel_launch(void* const* d_in, const int* in_sizes, int n_in,
                              void* d_out, int out_size, void* d_ws, size_t ws_size,
                              hipStream_t stream) {
    const float* x    = (const float*)d_in[0];
    const int*  ei    = (const int*)d_in[1];
    const int*  batch = (const int*)d_in[2];
    const float* ea   = (const float*)d_in[3];
    const float* Wemb = (const float*)d_in[4];
    const float* bemb = (const float*)d_in[5];
    const float* pW1  = (const float*)d_in[6];
    const float* pb1  = (const float*)d_in[7];
    const float* pW2  = (const float*)d_in[8];
    const float* pW3  = (const float*)d_in[9];
    const float* pb3  = (const float*)d_in[10];
    const float* Wf1  = (const float*)d_in[11];
    const float* bf1v = (const float*)d_in[12];
    const float* Wf2  = (const float*)d_in[13];
    const float* bf2v = (const float*)d_in[14];
    float* out = (float*)d_out;

    const int* src = ei;
    const int* dst = ei + N_EDGES;

    // ---- workspace layout ----
    const size_t NH = (size_t)N_NODES * H;
    char* p = (char*)d_ws;
    ushort* h       = (ushort*)p;            p += NH * 2;           // 12.8 MB
    ushort* a       = (ushort*)p;            p += NH * 2;           // 12.8 MB
    ushort* aggb    = (ushort*)p;            p += NH * 2;           // 12.8 MB
    unsigned* epack = (unsigned*)p;          p += (size_t)N_EDGES * 4;  // 6.4 MB
    int*   histM    = (int*)p;               p += MHIST * 4;
    int*   incl     = (int*)p;               p += MHIST * 4;
    int*   ebase    = (int*)p;               p += MHIST * 4;
    int*   partials = (int*)p;               p += 512 * 4;
    int*   chunk_off= (int*)p;               p += 512 * 4;
    int*   bkt_ptr  = (int*)p;               p += (NBKT + 1) * 4;
    int*   row_ptr  = (int*)p;               p += (N_NODES + 1) * 4;
    float* degw     = (float*)p;             p += N_NODES * 4;
    // staging overlays a/aggb (dead until lin kernels; build completes first)
    unsigned* eb_se = (unsigned*)a;          // 6.4 MB  (a region: 12.8 MB)
    int*     eb_dst = (int*)aggb;            // 6.4 MB  (aggb region: 12.8 MB)

    // ---- CSR build: two-level LDS-atomic counting sort (no global atomics) ----
    hist1_kernel<<<NBLK, 256, 0, stream>>>(dst, histM);
    gscan1_kernel<<<MHIST / 512, 512, 0, stream>>>(histM, incl, partials);
    gscan2_kernel<<<1, 512, 0, stream>>>(partials, chunk_off, MHIST / 512);
    gscan3_kernel<<<(MHIST + 255) / 256, 256, 0, stream>>>(histM, incl, chunk_off, ebase, bkt_ptr);
    scatter1_kernel<<<NBLK, 256, 0, stream>>>(src, dst, ea, ebase, eb_se, eb_dst);
    bucket_kernel<<<NBKT, 512, 0, stream>>>(bkt_ptr, eb_se, eb_dst, row_ptr, degw, epack);

    embed_kernel<<<(N_NODES * H + 255) / 256, 256, 0, stream>>>(x, Wemb, bemb, h);

    for (int l = 0; l < LAYERS; ++l) {
        linAB_kernel<<<512, 256, 0, stream>>>(
            h, degw,
            pW1 + (size_t)l * H * H, pb1 + (size_t)l * H,
            pW2 + (size_t)l * H * H,
            pW3 + (size_t)l * H * H, pb3 + (size_t)l * H,
            a, aggb);
        gather_kernel<<<(N_NODES + 3) / 4, 256, 0, stream>>>(row_ptr, epack, a, aggb, h);
    }

    poolhead_kernel<<<N_GRAPHS, 256, 0, stream>>>(h, batch, Wf1, bf1v, Wf2, bf2v, out);
}

// Round 11
// 331.949 us; speedup vs baseline: 4.7571x; 1.0788x over previous
//
#include <hip/hip_runtime.h>

#define N_NODES 100000
#define N_EDGES 1600000
#define N_GRAPHS 512
#define X_DIM 4
#define H 64
#define LAYERS 3
#define NUM_CLASS 3
#define NBLK 256            // partition blocks
#define EPB (N_EDGES / NBLK)  // 6250 edges per partition block
#define BKT_BITS 9
#define BKT_SZ 512          // nodes per bucket
#define NBKT ((N_NODES + BKT_SZ - 1) / BKT_SZ)  // 196
#define MHIST (NBKT * NBLK)  // 50176, divisible by 512
#define LROW 72             // padded LDS row (shorts): 144 B = 16B-aligned per row
#define NCHUNKS ((N_NODES + 63) / 64)  // 1563

typedef unsigned short ushort;
typedef short bf16x8 __attribute__((ext_vector_type(8)));
typedef unsigned short ush8 __attribute__((ext_vector_type(8)));
typedef float floatx4 __attribute__((ext_vector_type(4)));

__device__ __forceinline__ ushort f2bf(float v) {
    unsigned u = __float_as_uint(v);
    unsigned r = (u + 0x7fff + ((u >> 16) & 1)) >> 16;  // round-nearest-even
    return (ushort)r;
}
__device__ __forceinline__ float bf2f(ushort s) {
    return __uint_as_float(((unsigned)s) << 16);
}

// ---------------- precompute: G_i = Wemb @ W_i (4x64), C_i = bemb@W_i (+bias) ----------------
__global__ void precomp_kernel(const float* __restrict__ Wemb, const float* __restrict__ bemb,
                               const float* __restrict__ W1, const float* __restrict__ b1,
                               const float* __restrict__ W2, const float* __restrict__ W3,
                               const float* __restrict__ b3,
                               float* __restrict__ G, float* __restrict__ C) {
    int f = threadIdx.x;
    if (f >= H) return;
    const float* Ws[3] = {W1, W2, W3};
#pragma unroll
    for (int wsel = 0; wsel < 3; ++wsel) {
        const float* W = Ws[wsel];
#pragma unroll
        for (int c = 0; c < X_DIM; ++c) {
            float g = 0.f;
            for (int k = 0; k < H; ++k) g += Wemb[c * H + k] * W[k * H + f];
            G[wsel * 256 + c * H + f] = g;
        }
        float cb = (wsel == 0) ? b1[f] : (wsel == 2) ? b3[f] : 0.f;
        for (int k = 0; k < H; ++k) cb += bemb[k] * W[k * H + f];
        C[wsel * H + f] = cb;
    }
}

// ---------------- phase A: per-block bucket histogram (LDS atomics only) ----------------
__global__ __launch_bounds__(256) void hist1_kernel(const int* __restrict__ dst,
                                                    int* __restrict__ histM) {
    __shared__ int hist[NBKT];
    int t = threadIdx.x, b = blockIdx.x;
    for (int i = t; i < NBKT; i += 256) hist[i] = 0;
    __syncthreads();
    int e0 = b * EPB;
    for (int j = t; j < EPB; j += 256) {
        int d = dst[e0 + j];
        atomicAdd(hist + (d >> BKT_BITS), 1);
    }
    __syncthreads();
    for (int i = t; i < NBKT; i += 256) histM[i * NBLK + b] = hist[i];
}

// ---------------- generic scan over MHIST entries ----------------
__global__ __launch_bounds__(512) void gscan1_kernel(const int* __restrict__ v,
                                                     int* __restrict__ incl,
                                                     int* __restrict__ partials) {
    __shared__ int s[512];
    int tid = threadIdx.x;
    int i = blockIdx.x * 512 + tid;
    int x = (i < MHIST) ? v[i] : 0;
    s[tid] = x;
    for (int off = 1; off < 512; off <<= 1) {
        __syncthreads();
        int tv = (tid >= off) ? s[tid - off] : 0;
        __syncthreads();
        s[tid] += tv;
    }
    __syncthreads();
    if (i < MHIST) incl[i] = s[tid];
    if (tid == 511) partials[blockIdx.x] = s[tid];
}

__global__ __launch_bounds__(512) void gscan2_kernel(const int* __restrict__ partials,
                                                     int* __restrict__ chunk_off, int nchunk) {
    __shared__ int s[512];
    int tid = threadIdx.x;
    s[tid] = (tid < nchunk) ? partials[tid] : 0;
    for (int off = 1; off < 512; off <<= 1) {
        __syncthreads();
        int tv = (tid >= off) ? s[tid - off] : 0;
        __syncthreads();
        s[tid] += tv;
    }
    __syncthreads();
    int excl = (tid == 0) ? 0 : s[tid - 1];
    __syncthreads();
    if (tid < nchunk) chunk_off[tid] = excl;
}

__global__ void gscan3_kernel(const int* __restrict__ v, const int* __restrict__ incl,
                              const int* __restrict__ chunk_off,
                              int* __restrict__ ebase, int* __restrict__ bkt_ptr) {
    int i = blockIdx.x * 256 + threadIdx.x;
    if (i >= MHIST) return;
    int e = incl[i] + chunk_off[i >> 9] - v[i];
    ebase[i] = e;
    if ((i & (NBLK - 1)) == 0) bkt_ptr[i / NBLK] = e;
    if (i == MHIST - 1) bkt_ptr[NBKT] = e + v[i];
}

// ---------------- phase B: partition edges into bucket order (LDS cursors) ----------------
// packed edge word: src (17 bits) << 15 | bf16(ea) low 15 bits (sign always 0)
__global__ __launch_bounds__(256) void scatter1_kernel(
    const int* __restrict__ src, const int* __restrict__ dst, const float* __restrict__ ea,
    const int* __restrict__ ebase, unsigned* __restrict__ eb_se, int* __restrict__ eb_dst) {
    __shared__ int cur[NBKT];
    int t = threadIdx.x, b = blockIdx.x;
    for (int i = t; i < NBKT; i += 256) cur[i] = ebase[i * NBLK + b];
    __syncthreads();
    int e0 = b * EPB;
    for (int j = t; j < EPB; j += 256) {
        int e = e0 + j;
        int d = dst[e];
        int k = d >> BKT_BITS;
        int pos = atomicAdd(cur + k, 1);
        eb_se[pos] = ((unsigned)src[e] << 15) | (unsigned)f2bf(ea[e]);
        eb_dst[pos] = d;
    }
}

// ---------------- phase C: per-bucket CSR build + degw (LDS atomics only) ----------------
__global__ __launch_bounds__(512) void bucket_kernel(
    const int* __restrict__ bkt_ptr, const unsigned* __restrict__ eb_se,
    const int* __restrict__ eb_dst,
    int* __restrict__ row_ptr, float* __restrict__ degw, unsigned* __restrict__ epack) {
    __shared__ int cnt[BKT_SZ];
    __shared__ float dws[BKT_SZ];
    __shared__ int s[BKT_SZ];
    __shared__ int cur[BKT_SZ];
    int k = blockIdx.x, t = threadIdx.x;
    int base = k << BKT_BITS;
    int nn = N_NODES - base;
    if (nn > BKT_SZ) nn = BKT_SZ;
    cnt[t] = 0;
    dws[t] = 0.0f;
    __syncthreads();
    int beg = bkt_ptr[k], end = bkt_ptr[k + 1];
    for (int j = beg + t; j < end; j += 512) {
        int d = eb_dst[j] - base;
        atomicAdd(cnt + d, 1);
        atomicAdd(dws + d, __uint_as_float((eb_se[j] & 0x7FFFu) << 16));
    }
    __syncthreads();
    s[t] = cnt[t];
    for (int off = 1; off < 512; off <<= 1) {
        __syncthreads();
        int tv = (t >= off) ? s[t - off] : 0;
        __syncthreads();
        s[t] += tv;
    }
    __syncthreads();
    int rstart = beg + s[t] - cnt[t];
    if (t < nn) {
        row_ptr[base + t] = rstart;
        degw[base + t] = dws[t];
        cur[t] = rstart;
    }
    __syncthreads();
    for (int j = beg + t; j < end; j += 512) {
        unsigned se = eb_se[j];
        int d = eb_dst[j] - base;
        int pos = atomicAdd(cur + d, 1);
        epack[pos] = se;
    }
    if (k == NBKT - 1 && t == 0) row_ptr[N_NODES] = N_EDGES;
}

// ---------------- xgather: mx[d] = sum_in ea * x[src]  (4-dim, f32, L2-resident) ----------------
// wave = 1 node; lane = q*2+cp: edge slot q (0..31), component pair cp (0/1)
__global__ __launch_bounds__(256) void xgather_kernel(
    const int* __restrict__ row_ptr, const unsigned* __restrict__ epack,
    const float* __restrict__ x, float* __restrict__ mx) {
    int n = blockIdx.x * 4 + (threadIdx.x >> 6);
    if (n >= N_NODES) return;
    int lane = threadIdx.x & 63;
    int q = lane >> 1, cp = lane & 1;
    int beg = row_ptr[n], end = row_ptr[n + 1];
    float a0 = 0.f, a1 = 0.f;
    for (int j = beg; j < end; j += 32) {
        int jk = j + q;
        unsigned w = (jk < end) ? epack[jk] : 0u;
        float2 xv = *(const float2*)&x[(size_t)(w >> 15) * X_DIM + cp * 2];
        float e = __uint_as_float((w & 0x7FFFu) << 16);
        a0 += e * xv.x;
        a1 += e * xv.y;
    }
#pragma unroll
    for (int mask = 2; mask <= 32; mask <<= 1) {
        a0 += __shfl_xor(a0, mask);
        a1 += __shfl_xor(a1, mask);
    }
    if (lane < 2) {
        mx[(size_t)n * X_DIM + lane * 2] = a0;
        mx[(size_t)n * X_DIM + lane * 2 + 1] = a1;
    }
}

// ---------------- combine (layer 1): h = bf16(relu(mx@G1 + dw*c1 + x@G3 + c3 - (x@G2+c2)*dw)) --
__global__ void combine_kernel(const float* __restrict__ x, const float* __restrict__ mx,
                               const float* __restrict__ degw,
                               const float* __restrict__ G, const float* __restrict__ C,
                               ushort* __restrict__ h) {
    int i = blockIdx.x * blockDim.x + threadIdx.x;
    if (i >= N_NODES * H) return;
    int n = i >> 6, f = i & 63;
    floatx4 xv = *(const floatx4*)&x[(size_t)n * X_DIM];
    floatx4 mv = *(const floatx4*)&mx[(size_t)n * X_DIM];
    float dw = degw[n];
    float t1 = mv[0] * G[f] + mv[1] * G[64 + f] + mv[2] * G[128 + f] + mv[3] * G[192 + f];
    float t2 = xv[0] * G[256 + f] + xv[1] * G[320 + f] + xv[2] * G[384 + f] + xv[3] * G[448 + f];
    float t3 = xv[0] * G[512 + f] + xv[1] * G[576 + f] + xv[2] * G[640 + f] + xv[3] * G[704 + f];
    float v = t1 + dw * C[f] + t3 + C[128 + f] - (t2 + C[64 + f]) * dw;
    h[i] = f2bf(fmaxf(v, 0.0f));
}

// ---------------- gather: m[d] = bf16(sum_in ea*h[src]) ----------------
// wave = 1 node; lane = q*8+s: edge-slot q (0..7), feature octet s
__global__ __launch_bounds__(256) void gather_kernel(
    const int* __restrict__ row_ptr, const unsigned* __restrict__ epack,
    const ushort* __restrict__ h, ushort* __restrict__ m) {
    int n = blockIdx.x * 4 + (threadIdx.x >> 6);
    if (n >= N_NODES) return;
    int lane = threadIdx.x & 63;
    int q = lane >> 3, s = lane & 7;
    int beg = row_ptr[n], end = row_ptr[n + 1];
    float acc[8] = {0.f, 0.f, 0.f, 0.f, 0.f, 0.f, 0.f, 0.f};
    for (int j = beg; j < end; j += 32) {
        unsigned w[4];
#pragma unroll
        for (int k = 0; k < 4; ++k) {
            int jk = j + k * 8 + q;
            w[k] = (jk < end) ? epack[jk] : 0u;
        }
        ush8 av[4];
#pragma unroll
        for (int k = 0; k < 4; ++k)
            av[k] = *(const ush8*)&h[(size_t)(w[k] >> 15) * H + s * 8];
#pragma unroll
        for (int k = 0; k < 4; ++k) {
            float e = __uint_as_float((w[k] & 0x7FFFu) << 16);
#pragma unroll
            for (int i = 0; i < 8; ++i)
                acc[i] += e * bf2f((ushort)av[k][i]);
        }
    }
#pragma unroll
    for (int i = 0; i < 8; ++i) {
        acc[i] += __shfl_xor(acc[i], 8);
        acc[i] += __shfl_xor(acc[i], 16);
        acc[i] += __shfl_xor(acc[i], 32);
    }
    if (q == 0) {
        ush8 r;
#pragma unroll
        for (int i = 0; i < 8; ++i) r[i] = (short)f2bf(acc[i]);
        *(ush8*)&m[(size_t)n * H + s * 8] = r;
    }
}

// ---------------- linC: h = bf16(relu(m@W1 + dw*b1 + h@W3 + b3 - (h@W2)*dw))  in-place ------
// Persistent blocks; B-fragments in registers once per block; stages h+m tiles in LDS.
__global__ __launch_bounds__(256) void linC_kernel(
    ushort* __restrict__ h, const ushort* __restrict__ m,
    const float* __restrict__ degw,
    const float* __restrict__ W1, const float* __restrict__ bias1,
    const float* __restrict__ W2, const float* __restrict__ W3,
    const float* __restrict__ bias3) {
    __shared__ alignas(16) ushort ah[64 * LROW];
    __shared__ alignas(16) ushort am[64 * LROW];
    int t = threadIdx.x;
    int wv = t >> 6, lane = t & 63;
    int quad = lane >> 4, m16 = lane & 15;
    int f = wv * 16 + m16;
    bf16x8 B[3][2][2];  // [weight][khalf][hi/lo]
    const float* Ws[3] = {W1, W2, W3};
#pragma unroll
    for (int wsel = 0; wsel < 3; ++wsel) {
#pragma unroll
        for (int kh = 0; kh < 2; ++kh) {
#pragma unroll
            for (int j = 0; j < 8; ++j) {
                float w = Ws[wsel][(kh * 32 + quad * 8 + j) * H + f];
                ushort hi = f2bf(w);
                B[wsel][kh][0][j] = (short)hi;
                B[wsel][kh][1][j] = (short)f2bf(w - bf2f(hi));
            }
        }
    }
    float bb1 = bias1[f], bb3 = bias3[f];
    for (int chunk = blockIdx.x; chunk < NCHUNKS; chunk += gridDim.x) {
        int nbase = chunk * 64;
        __syncthreads();  // protect LDS reuse across chunk iterations
        for (int v = t; v < 64 * 8; v += 256) {
            int nl = v >> 3, k0 = (v & 7) * 8;
            int n = nbase + nl;
            ush8 vh = {0, 0, 0, 0, 0, 0, 0, 0};
            ush8 vm = {0, 0, 0, 0, 0, 0, 0, 0};
            if (n < N_NODES) {
                vh = *(const ush8*)&h[(size_t)n * H + k0];
                vm = *(const ush8*)&m[(size_t)n * H + k0];
            }
            *(ush8*)&ah[nl * LROW + k0] = vh;
            *(ush8*)&am[nl * LROW + k0] = vm;
        }
        __syncthreads();
#pragma unroll
        for (int ng = 0; ng < 4; ++ng) {
            int abase = (ng * 16 + m16) * LROW + quad * 8;
            bf16x8 Ah0 = *(const bf16x8*)&ah[abase];
            bf16x8 Ah1 = *(const bf16x8*)&ah[abase + 32];
            bf16x8 Am0 = *(const bf16x8*)&am[abase];
            bf16x8 Am1 = *(const bf16x8*)&am[abase + 32];
            floatx4 acc1 = {0.f, 0.f, 0.f, 0.f};
            floatx4 acc2 = {0.f, 0.f, 0.f, 0.f};
            floatx4 acc3 = {0.f, 0.f, 0.f, 0.f};
            acc1 = __builtin_amdgcn_mfma_f32_16x16x32_bf16(Am0, B[0][0][0], acc1, 0, 0, 0);
            acc1 = __builtin_amdgcn_mfma_f32_16x16x32_bf16(Am0, B[0][0][1], acc1, 0, 0, 0);
            acc1 = __builtin_amdgcn_mfma_f32_16x16x32_bf16(Am1, B[0][1][0], acc1, 0, 0, 0);
            acc1 = __builtin_amdgcn_mfma_f32_16x16x32_bf16(Am1, B[0][1][1], acc1, 0, 0, 0);
            acc2 = __builtin_amdgcn_mfma_f32_16x16x32_bf16(Ah0, B[1][0][0], acc2, 0, 0, 0);
            acc2 = __builtin_amdgcn_mfma_f32_16x16x32_bf16(Ah0, B[1][0][1], acc2, 0, 0, 0);
            acc2 = __builtin_amdgcn_mfma_f32_16x16x32_bf16(Ah1, B[1][1][0], acc2, 0, 0, 0);
            acc2 = __builtin_amdgcn_mfma_f32_16x16x32_bf16(Ah1, B[1][1][1], acc2, 0, 0, 0);
            acc3 = __builtin_amdgcn_mfma_f32_16x16x32_bf16(Ah0, B[2][0][0], acc3, 0, 0, 0);
            acc3 = __builtin_amdgcn_mfma_f32_16x16x32_bf16(Ah0, B[2][0][1], acc3, 0, 0, 0);
            acc3 = __builtin_amdgcn_mfma_f32_16x16x32_bf16(Ah1, B[2][1][0], acc3, 0, 0, 0);
            acc3 = __builtin_amdgcn_mfma_f32_16x16x32_bf16(Ah1, B[2][1][1], acc3, 0, 0, 0);
            int nrow = nbase + ng * 16 + quad * 4;
#pragma unroll
            for (int r = 0; r < 4; ++r) {
                int n = nrow + r;
                if (n < N_NODES) {
                    float dw = degw[n];
                    float v = acc1[r] + dw * bb1 + acc3[r] + bb3 - acc2[r] * dw;
                    h[(size_t)n * H + f] = f2bf(fmaxf(v, 0.0f));
                }
            }
        }
    }
}

// ---------------- fused mean-pool + MLP head (batch is sorted) ----------------
__device__ __forceinline__ int lower_bound(const int* __restrict__ arr, int n, int key) {
    int lo = 0, hi = n;
    while (lo < hi) {
        int mid = (lo + hi) >> 1;
        if (arr[mid] < key) lo = mid + 1; else hi = mid;
    }
    return lo;
}

__global__ __launch_bounds__(256) void poolhead_kernel(
    const ushort* __restrict__ h, const int* __restrict__ batch,
    const float* __restrict__ Wf1, const float* __restrict__ bf1v,
    const float* __restrict__ Wf2, const float* __restrict__ bf2v,
    float* __restrict__ out) {
    __shared__ float psum[4][H];
    __shared__ float gx[H];
    __shared__ float hid[2 * H];
    int g = blockIdx.x, t = threadIdx.x;
    int s = lower_bound(batch, N_NODES, g);
    int e = lower_bound(batch, N_NODES, g + 1);
    int lane = t & 63, wv = t >> 6;
    int o = lane & 7;
    int nd = t >> 3;
    float acc[8] = {0.f, 0.f, 0.f, 0.f, 0.f, 0.f, 0.f, 0.f};
    for (int n = s + nd; n < e; n += 32) {
        ush8 v = *(const ush8*)&h[(size_t)n * H + o * 8];
#pragma unroll
        for (int i = 0; i < 8; ++i) acc[i] += bf2f((ushort)v[i]);
    }
#pragma unroll
    for (int i = 0; i < 8; ++i) {
        acc[i] += __shfl_xor(acc[i], 8);
        acc[i] += __shfl_xor(acc[i], 16);
        acc[i] += __shfl_xor(acc[i], 32);
    }
    if (lane < 8) {
#pragma unroll
        for (int i = 0; i < 8; ++i) psum[wv][o * 8 + i] = acc[i];
    }
    __syncthreads();
    if (t < H) {
        float c = (float)(e - s);
        gx[t] = (psum[0][t] + psum[1][t] + psum[2][t] + psum[3][t]) / fmaxf(c, 1.0f);
    }
    __syncthreads();
    if (t < 2 * H) {
        float acc2 = bf1v[t];
        for (int k = 0; k < H; ++k) acc2 += gx[k] * Wf1[k * 2 * H + t];
        hid[t] = fmaxf(acc2, 0.0f);
    }
    __syncthreads();
    if (t < NUM_CLASS) {
        float o2 = bf2v[t];
        for (int k = 0; k < 2 * H; ++k) o2 += hid[k] * Wf2[k * NUM_CLASS + t];
        out[g * NUM_CLASS + t] = o2;
    }
}

extern "C" void kernel_launch(void* const* d_in, const int* in_sizes, int n_in,
                              void* d_out, int out_size, void* d_ws, size_t ws_size,
                              hipStream_t stream) {
    const float* x    = (const float*)d_in[0];
    const int*  ei    = (const int*)d_in[1];
    const int*  batch = (const int*)d_in[2];
    const float* ea   = (const float*)d_in[3];
    const float* Wemb = (const float*)d_in[4];
    const float* bemb = (const float*)d_in[5];
    const float* pW1  = (const float*)d_in[6];
    const float* pb1  = (const float*)d_in[7];
    const float* pW2  = (const float*)d_in[8];
    const float* pW3  = (const float*)d_in[9];
    const float* pb3  = (const float*)d_in[10];
    const float* Wf1  = (const float*)d_in[11];
    const float* bf1v = (const float*)d_in[12];
    const float* Wf2  = (const float*)d_in[13];
    const float* bf2v = (const float*)d_in[14];
    float* out = (float*)d_out;

    const int* src = ei;
    const int* dst = ei + N_EDGES;

    // ---- workspace layout ----
    const size_t NH = (size_t)N_NODES * H;
    char* p = (char*)d_ws;
    ushort* h       = (ushort*)p;            p += NH * 2;               // 12.8 MB
    ushort* m       = (ushort*)p;            p += NH * 2;               // 12.8 MB
    float*  mx      = (float*)p;             p += (size_t)N_NODES * X_DIM * 4;  // 1.6 MB
    unsigned* epack = (unsigned*)p;          p += (size_t)N_EDGES * 4;  // 6.4 MB
    int*   histM    = (int*)p;               p += MHIST * 4;
    int*   incl     = (int*)p;               p += MHIST * 4;
    int*   ebase    = (int*)p;               p += MHIST * 4;
    int*   partials = (int*)p;               p += 512 * 4;
    int*   chunk_off= (int*)p;               p += 512 * 4;
    int*   bkt_ptr  = (int*)p;               p += (NBKT + 1) * 4;
    int*   row_ptr  = (int*)p;               p += (N_NODES + 1) * 4;
    float* degw     = (float*)p;             p += N_NODES * 4;
    float* Gbuf     = (float*)p;             p += 3 * 256 * 4;          // G1,G2,G3 (4x64 each)
    float* Cbuf     = (float*)p;             p += 3 * 64 * 4;           // c1,c2,c3
    // staging overlays m/h (dead until xgather/combine; build completes first)
    unsigned* eb_se = (unsigned*)m;          // 6.4 MB  (m region: 12.8 MB)
    int*     eb_dst = (int*)h;               // 6.4 MB  (h region: 12.8 MB)

    // ---- precompute folded layer-1 weights ----
    precomp_kernel<<<1, 64, 0, stream>>>(Wemb, bemb, pW1, pb1, pW2, pW3, pb3, Gbuf, Cbuf);

    // ---- CSR build: two-level LDS-atomic counting sort (no global atomics) ----
    hist1_kernel<<<NBLK, 256, 0, stream>>>(dst, histM);
    gscan1_kernel<<<MHIST / 512, 512, 0, stream>>>(histM, incl, partials);
    gscan2_kernel<<<1, 512, 0, stream>>>(partials, chunk_off, MHIST / 512);
    gscan3_kernel<<<(MHIST + 255) / 256, 256, 0, stream>>>(histM, incl, chunk_off, ebase, bkt_ptr);
    scatter1_kernel<<<NBLK, 256, 0, stream>>>(src, dst, ea, ebase, eb_se, eb_dst);
    bucket_kernel<<<NBKT, 512, 0, stream>>>(bkt_ptr, eb_se, eb_dst, row_ptr, degw, epack);

    // ---- layer 1 via x-gather (x is 1.6 MB -> L2-resident; 4-dim rows) ----
    xgather_kernel<<<(N_NODES + 3) / 4, 256, 0, stream>>>(row_ptr, epack, x, mx);
    combine_kernel<<<(N_NODES * H + 255) / 256, 256, 0, stream>>>(x, mx, degw, Gbuf, Cbuf, h);

    // ---- layers 2,3: gather m from h, then MFMA lin in-place ----
    for (int l = 1; l < LAYERS; ++l) {
        gather_kernel<<<(N_NODES + 3) / 4, 256, 0, stream>>>(row_ptr, epack, h, m);
        linC_kernel<<<512, 256, 0, stream>>>(
            h, m, degw,
            pW1 + (size_t)l * H * H, pb1 + (size_t)l * H,
            pW2 + (size_t)l * H * H,
            pW3 + (size_t)l * H * H, pb3 + (size_t)l * H);
    }

    poolhead_kernel<<<N_GRAPHS, 256, 0, stream>>>(h, batch, Wf1, bf1v, Wf2, bf2v, out);
}

// Round 13
// 315.367 us; speedup vs baseline: 5.0073x; 1.0526x over previous
//
#include <hip/hip_runtime.h>

#define N_NODES 100000
#define N_EDGES 1600000
#define N_GRAPHS 512
#define X_DIM 4
#define H 64
#define LAYERS 3
#define NUM_CLASS 3
#define NBLK 256            // partition blocks
#define EPB (N_EDGES / NBLK)  // 6250 edges per partition block
#define BKT_BITS 9
#define BKT_SZ 512          // nodes per bucket
#define NBKT ((N_NODES + BKT_SZ - 1) / BKT_SZ)  // 196
#define MHIST (NBKT * NBLK)  // 50176, divisible by 512
#define NCH (MHIST / 512)    // 98 scan chunks
#define LROW 72              // padded LDS row (shorts): 144 B, 16B-aligned rows
#define NCHUNKS ((N_NODES + 63) / 64)  // 1563

typedef unsigned short ushort;
typedef short bf16x8 __attribute__((ext_vector_type(8)));
typedef unsigned short ush8 __attribute__((ext_vector_type(8)));
typedef float floatx4 __attribute__((ext_vector_type(4)));

__device__ __forceinline__ ushort f2bf(float v) {
    unsigned u = __float_as_uint(v);
    unsigned r = (u + 0x7fff + ((u >> 16) & 1)) >> 16;  // round-nearest-even
    return (ushort)r;
}
__device__ __forceinline__ float bf2f(ushort s) {
    return __uint_as_float(((unsigned)s) << 16);
}

// ---------------- phase A: bucket histogram + folded layer-1 precompute ----------------
// block 0 lanes<64 also compute G_i = Wemb@W_i (4x64), C_i = bemb@W_i (+bias)
__global__ __launch_bounds__(256) void hist1_kernel(
    const int* __restrict__ dst, int* __restrict__ histM,
    const float* __restrict__ Wemb, const float* __restrict__ bemb,
    const float* __restrict__ W1, const float* __restrict__ b1,
    const float* __restrict__ W2, const float* __restrict__ W3,
    const float* __restrict__ b3,
    float* __restrict__ G, float* __restrict__ C) {
    __shared__ int hist[NBKT];
    int t = threadIdx.x, b = blockIdx.x;
    for (int i = t; i < NBKT; i += 256) hist[i] = 0;
    __syncthreads();
    int e0 = b * EPB;
    for (int j = t; j < EPB; j += 256) {
        int d = dst[e0 + j];
        atomicAdd(hist + (d >> BKT_BITS), 1);
    }
    __syncthreads();
    for (int i = t; i < NBKT; i += 256) histM[i * NBLK + b] = hist[i];
    if (b == 0 && t < H) {
        int f = t;
        const float* Ws[3] = {W1, W2, W3};
#pragma unroll
        for (int wsel = 0; wsel < 3; ++wsel) {
            const float* W = Ws[wsel];
#pragma unroll
            for (int c = 0; c < X_DIM; ++c) {
                float g = 0.f;
                for (int k = 0; k < H; ++k) g += Wemb[c * H + k] * W[k * H + f];
                G[wsel * 256 + c * H + f] = g;
            }
            float cb = (wsel == 0) ? b1[f] : (wsel == 2) ? b3[f] : 0.f;
            for (int k = 0; k < H; ++k) cb += bemb[k] * W[k * H + f];
            C[wsel * H + f] = cb;
        }
    }
}

// ---------------- per-512-chunk inclusive scan over MHIST ----------------
__global__ __launch_bounds__(512) void gscan1_kernel(const int* __restrict__ v,
                                                     int* __restrict__ incl,
                                                     int* __restrict__ partials) {
    __shared__ int s[512];
    int tid = threadIdx.x;
    int i = blockIdx.x * 512 + tid;
    int x = (i < MHIST) ? v[i] : 0;
    s[tid] = x;
    for (int off = 1; off < 512; off <<= 1) {
        __syncthreads();
        int tv = (tid >= off) ? s[tid - off] : 0;
        __syncthreads();
        s[tid] += tv;
    }
    __syncthreads();
    if (i < MHIST) incl[i] = s[tid];
    if (tid == 511) partials[blockIdx.x] = s[tid];
}

// ---------------- phase B: partition edges (fused chunk-scan + ebase; LDS cursors) ----------------
// packed edge word: src(17 bits)<<15 | bf16(ea) low 15 bits (ea >= 0 so sign bit is 0)
__global__ __launch_bounds__(256) void scatter1_kernel(
    const int* __restrict__ src, const int* __restrict__ dst, const float* __restrict__ ea,
    const int* __restrict__ histM, const int* __restrict__ incl,
    const int* __restrict__ partials,
    unsigned* __restrict__ eb_se, int* __restrict__ eb_dst, int* __restrict__ bkt_ptr) {
    __shared__ int coff[128];
    __shared__ int cur[NBKT];
    int t = threadIdx.x, b = blockIdx.x;
    if (t < 128) coff[t] = (t < NCH) ? partials[t] : 0;
    __syncthreads();
    for (int off = 1; off < 128; off <<= 1) {
        int tv = (t < 128 && t >= off) ? coff[t - off] : 0;
        __syncthreads();
        if (t < 128) coff[t] += tv;
        __syncthreads();
    }
    for (int i = t; i < NBKT; i += 256) {
        int idx = i * NBLK + b;
        int ch = idx >> 9;
        int off0 = (ch == 0) ? 0 : coff[ch - 1];
        cur[i] = incl[idx] - histM[idx] + off0;  // global exclusive prefix
    }
    __syncthreads();
    if (b == 0) {
        for (int i = t; i < NBKT; i += 256) bkt_ptr[i] = cur[i];
        if (t == 0) bkt_ptr[NBKT] = N_EDGES;
    }
    int e0 = b * EPB;
    for (int j = t; j < EPB; j += 256) {
        int e = e0 + j;
        int d = dst[e];
        int k = d >> BKT_BITS;
        int pos = atomicAdd(cur + k, 1);
        eb_se[pos] = ((unsigned)src[e] << 15) | (unsigned)f2bf(ea[e]);
        eb_dst[pos] = d;
    }
}

// ---------------- phase C: per-bucket CSR build + degw (LDS atomics only) ----------------
__global__ __launch_bounds__(512) void bucket_kernel(
    const int* __restrict__ bkt_ptr, const unsigned* __restrict__ eb_se,
    const int* __restrict__ eb_dst,
    int* __restrict__ row_ptr, float* __restrict__ degw, unsigned* __restrict__ epack) {
    __shared__ int cnt[BKT_SZ];
    __shared__ float dws[BKT_SZ];
    __shared__ int s[BKT_SZ];
    __shared__ int cur[BKT_SZ];
    int k = blockIdx.x, t = threadIdx.x;
    int base = k << BKT_BITS;
    int nn = N_NODES - base;
    if (nn > BKT_SZ) nn = BKT_SZ;
    cnt[t] = 0;
    dws[t] = 0.0f;
    __syncthreads();
    int beg = bkt_ptr[k], end = bkt_ptr[k + 1];
    for (int j = beg + t; j < end; j += 512) {
        int d = eb_dst[j] - base;
        atomicAdd(cnt + d, 1);
        atomicAdd(dws + d, __uint_as_float((eb_se[j] & 0x7FFFu) << 16));
    }
    __syncthreads();
    s[t] = cnt[t];
    for (int off = 1; off < 512; off <<= 1) {
        __syncthreads();
        int tv = (t >= off) ? s[t - off] : 0;
        __syncthreads();
        s[t] += tv;
    }
    __syncthreads();
    int rstart = beg + s[t] - cnt[t];
    if (t < nn) {
        row_ptr[base + t] = rstart;
        degw[base + t] = dws[t];
        cur[t] = rstart;
    }
    __syncthreads();
    for (int j = beg + t; j < end; j += 512) {
        unsigned se = eb_se[j];
        int d = eb_dst[j] - base;
        int pos = atomicAdd(cur + d, 1);
        epack[pos] = se;
    }
    if (k == NBKT - 1 && t == 0) row_ptr[N_NODES] = N_EDGES;
}

// ---------------- layer 1 (fused xgather + combine), wave = 1 node ----------------
// h = bf16(relu(mx@G1 + dw*C1 + x@G3 + C3 - (x@G2 + C2)*dw)), mx = sum_in ea*x[src]
__global__ __launch_bounds__(256) void layer1_kernel(
    const int* __restrict__ row_ptr, const unsigned* __restrict__ epack,
    const float* __restrict__ x, const float* __restrict__ degw,
    const float* __restrict__ G, const float* __restrict__ C,
    ushort* __restrict__ h) {
    int n = blockIdx.x * 4 + (threadIdx.x >> 6);
    if (n >= N_NODES) return;
    int lane = threadIdx.x & 63;
    float Gr[12], Cr[3];
#pragma unroll
    for (int i = 0; i < 12; ++i) Gr[i] = G[(i >> 2) * 256 + (i & 3) * 64 + lane];
#pragma unroll
    for (int i = 0; i < 3; ++i) Cr[i] = C[i * 64 + lane];
    int q2 = lane >> 1, cp = lane & 1;
    int beg = row_ptr[n], end = row_ptr[n + 1];
    float a0 = 0.f, a1 = 0.f;
    for (int j = beg; j < end; j += 32) {
        int jk = j + q2;
        unsigned w = (jk < end) ? epack[jk] : 0u;
        float2 xv = *(const float2*)&x[(size_t)(w >> 15) * X_DIM + cp * 2];
        float e = __uint_as_float((w & 0x7FFFu) << 16);
        a0 += e * xv.x;
        a1 += e * xv.y;
    }
#pragma unroll
    for (int mask = 2; mask <= 32; mask <<= 1) {
        a0 += __shfl_xor(a0, mask);
        a1 += __shfl_xor(a1, mask);
    }
    float mv0 = __shfl(a0, 0), mv1 = __shfl(a1, 0);
    float mv2 = __shfl(a0, 1), mv3 = __shfl(a1, 1);
    floatx4 xr = *(const floatx4*)&x[(size_t)n * X_DIM];
    float dw = degw[n];
    float t1 = mv0 * Gr[0] + mv1 * Gr[1] + mv2 * Gr[2] + mv3 * Gr[3];
    float t2 = xr[0] * Gr[4] + xr[1] * Gr[5] + xr[2] * Gr[6] + xr[3] * Gr[7];
    float t3 = xr[0] * Gr[8] + xr[1] * Gr[9] + xr[2] * Gr[10] + xr[3] * Gr[11];
    float v = t1 + dw * Cr[0] + t3 + Cr[2] - (t2 + Cr[1]) * dw;
    h[(size_t)n * H + lane] = f2bf(fmaxf(v, 0.0f));
}

// ---------------- gather: m[d] = bf16(sum_in ea*h[src]) ----------------
// wave = 1 node; lane = q*8+s: edge-slot q (0..7), feature octet s
__global__ __launch_bounds__(256) void gather_kernel(
    const int* __restrict__ row_ptr, const unsigned* __restrict__ epack,
    const ushort* __restrict__ h, ushort* __restrict__ m) {
    int n = blockIdx.x * 4 + (threadIdx.x >> 6);
    if (n >= N_NODES) return;
    int lane = threadIdx.x & 63;
    int q = lane >> 3, s = lane & 7;
    int beg = row_ptr[n], end = row_ptr[n + 1];
    float acc[8] = {0.f, 0.f, 0.f, 0.f, 0.f, 0.f, 0.f, 0.f};
    for (int j = beg; j < end; j += 32) {
        unsigned w[4];
#pragma unroll
        for (int k = 0; k < 4; ++k) {
            int jk = j + k * 8 + q;
            w[k] = (jk < end) ? epack[jk] : 0u;
        }
        ush8 av[4];
#pragma unroll
        for (int k = 0; k < 4; ++k)
            av[k] = *(const ush8*)&h[(size_t)(w[k] >> 15) * H + s * 8];
#pragma unroll
        for (int k = 0; k < 4; ++k) {
            float e = __uint_as_float((w[k] & 0x7FFFu) << 16);
#pragma unroll
            for (int i = 0; i < 8; ++i)
                acc[i] += e * bf2f((ushort)av[k][i]);
        }
    }
#pragma unroll
    for (int i = 0; i < 8; ++i) {
        acc[i] += __shfl_xor(acc[i], 8);
        acc[i] += __shfl_xor(acc[i], 16);
        acc[i] += __shfl_xor(acc[i], 32);
    }
    if (q == 0) {
        ush8 r;
#pragma unroll
        for (int i = 0; i < 8; ++i) r[i] = (short)f2bf(acc[i]);
        *(ush8*)&m[(size_t)n * H + s * 8] = r;
    }
}

// ---------------- linC: h = bf16(relu(m@W1 + dw*b1 + h@W3 + b3 - (h@W2)*dw))  in-place ------
// Persistent blocks; B-fragments in registers once per block; stages h+m tiles in LDS.
__global__ __launch_bounds__(256) void linC_kernel(
    ushort* __restrict__ h, const ushort* __restrict__ m,
    const float* __restrict__ degw,
    const float* __restrict__ W1, const float* __restrict__ bias1,
    const float* __restrict__ W2, const float* __restrict__ W3,
    const float* __restrict__ bias3) {
    __shared__ alignas(16) ushort ah[64 * LROW];
    __shared__ alignas(16) ushort am[64 * LROW];
    int t = threadIdx.x;
    int wv = t >> 6, lane = t & 63;
    int quad = lane >> 4, m16 = lane & 15;
    int f = wv * 16 + m16;
    bf16x8 B[3][2][2];  // [weight][khalf][hi/lo]
    const float* Ws[3] = {W1, W2, W3};
#pragma unroll
    for (int wsel = 0; wsel < 3; ++wsel) {
#pragma unroll
        for (int kh = 0; kh < 2; ++kh) {
#pragma unroll
            for (int j = 0; j < 8; ++j) {
                float w = Ws[wsel][(kh * 32 + quad * 8 + j) * H + f];
                ushort hi = f2bf(w);
                B[wsel][kh][0][j] = (short)hi;
                B[wsel][kh][1][j] = (short)f2bf(w - bf2f(hi));
            }
        }
    }
    float bb1 = bias1[f], bb3 = bias3[f];
    for (int chunk = blockIdx.x; chunk < NCHUNKS; chunk += gridDim.x) {
        int nbase = chunk * 64;
        __syncthreads();  // protect LDS reuse across chunk iterations
        for (int v = t; v < 64 * 8; v += 256) {
            int nl = v >> 3, k0 = (v & 7) * 8;
            int n = nbase + nl;
            ush8 vh = {0, 0, 0, 0, 0, 0, 0, 0};
            ush8 vm = {0, 0, 0, 0, 0, 0, 0, 0};
            if (n < N_NODES) {
                vh = *(const ush8*)&h[(size_t)n * H + k0];
                vm = *(const ush8*)&m[(size_t)n * H + k0];
            }
            *(ush8*)&ah[nl * LROW + k0] = vh;
            *(ush8*)&am[nl * LROW + k0] = vm;
        }
        __syncthreads();
#pragma unroll
        for (int ng = 0; ng < 4; ++ng) {
            int abase = (ng * 16 + m16) * LROW + quad * 8;
            bf16x8 Ah0 = *(const bf16x8*)&ah[abase];
            bf16x8 Ah1 = *(const bf16x8*)&ah[abase + 32];
            bf16x8 Am0 = *(const bf16x8*)&am[abase];
            bf16x8 Am1 = *(const bf16x8*)&am[abase + 32];
            floatx4 acc1 = {0.f, 0.f, 0.f, 0.f};
            floatx4 acc2 = {0.f, 0.f, 0.f, 0.f};
            floatx4 acc3 = {0.f, 0.f, 0.f, 0.f};
            acc1 = __builtin_amdgcn_mfma_f32_16x16x32_bf16(Am0, B[0][0][0], acc1, 0, 0, 0);
            acc1 = __builtin_amdgcn_mfma_f32_16x16x32_bf16(Am0, B[0][0][1], acc1, 0, 0, 0);
            acc1 = __builtin_amdgcn_mfma_f32_16x16x32_bf16(Am1, B[0][1][0], acc1, 0, 0, 0);
            acc1 = __builtin_amdgcn_mfma_f32_16x16x32_bf16(Am1, B[0][1][1], acc1, 0, 0, 0);
            acc2 = __builtin_amdgcn_mfma_f32_16x16x32_bf16(Ah0, B[1][0][0], acc2, 0, 0, 0);
            acc2 = __builtin_amdgcn_mfma_f32_16x16x32_bf16(Ah0, B[1][0][1], acc2, 0, 0, 0);
            acc2 = __builtin_amdgcn_mfma_f32_16x16x32_bf16(Ah1, B[1][1][0], acc2, 0, 0, 0);
            acc2 = __builtin_amdgcn_mfma_f32_16x16x32_bf16(Ah1, B[1][1][1], acc2, 0, 0, 0);
            acc3 = __builtin_amdgcn_mfma_f32_16x16x32_bf16(Ah0, B[2][0][0], acc3, 0, 0, 0);
            acc3 = __builtin_amdgcn_mfma_f32_16x16x32_bf16(Ah0, B[2][0][1], acc3, 0, 0, 0);
            acc3 = __builtin_amdgcn_mfma_f32_16x16x32_bf16(Ah1, B[2][1][0], acc3, 0, 0, 0);
            acc3 = __builtin_amdgcn_mfma_f32_16x16x32_bf16(Ah1, B[2][1][1], acc3, 0, 0, 0);
            int nrow = nbase + ng * 16 + quad * 4;
#pragma unroll
            for (int r = 0; r < 4; ++r) {
                int n = nrow + r;
                if (n < N_NODES) {
                    float dw = degw[n];
                    float v = acc1[r] + dw * bb1 + acc3[r] + bb3 - acc2[r] * dw;
                    h[(size_t)n * H + f] = f2bf(fmaxf(v, 0.0f));
                }
            }
        }
    }
}

// ---------------- fused mean-pool + MLP head (batch is sorted) ----------------
__device__ __forceinline__ int lower_bound(const int* __restrict__ arr, int n, int key) {
    int lo = 0, hi = n;
    while (lo < hi) {
        int mid = (lo + hi) >> 1;
        if (arr[mid] < key) lo = mid + 1; else hi = mid;
    }
    return lo;
}

__global__ __launch_bounds__(256) void poolhead_kernel(
    const ushort* __restrict__ h, const int* __restrict__ batch,
    const float* __restrict__ Wf1, const float* __restrict__ bf1v,
    const float* __restrict__ Wf2, const float* __restrict__ bf2v,
    float* __restrict__ out) {
    __shared__ float psum[4][H];
    __shared__ float gx[H];
    __shared__ float hid[2 * H];
    int g = blockIdx.x, t = threadIdx.x;
    int s = lower_bound(batch, N_NODES, g);
    int e = lower_bound(batch, N_NODES, g + 1);
    int lane = t & 63, wv = t >> 6;
    int o = lane & 7;
    int nd = t >> 3;
    float acc[8] = {0.f, 0.f, 0.f, 0.f, 0.f, 0.f, 0.f, 0.f};
    for (int n = s + nd; n < e; n += 32) {
        ush8 v = *(const ush8*)&h[(size_t)n * H + o * 8];
#pragma unroll
        for (int i = 0; i < 8; ++i) acc[i] += bf2f((ushort)v[i]);
    }
#pragma unroll
    for (int i = 0; i < 8; ++i) {
        acc[i] += __shfl_xor(acc[i], 8);
        acc[i] += __shfl_xor(acc[i], 16);
        acc[i] += __shfl_xor(acc[i], 32);
    }
    if (lane < 8) {
#pragma unroll
        for (int i = 0; i < 8; ++i) psum[wv][o * 8 + i] = acc[i];
    }
    __syncthreads();
    if (t < H) {
        float c = (float)(e - s);
        gx[t] = (psum[0][t] + psum[1][t] + psum[2][t] + psum[3][t]) / fmaxf(c, 1.0f);
    }
    __syncthreads();
    if (t < 2 * H) {
        float acc2 = bf1v[t];
        for (int k = 0; k < H; ++k) acc2 += gx[k] * Wf1[k * 2 * H + t];
        hid[t] = fmaxf(acc2, 0.0f);
    }
    __syncthreads();
    if (t < NUM_CLASS) {
        float o2 = bf2v[t];
        for (int k = 0; k < 2 * H; ++k) o2 += hid[k] * Wf2[k * NUM_CLASS + t];
        out[g * NUM_CLASS + t] = o2;
    }
}

extern "C" void kernel_launch(void* const* d_in, const int* in_sizes, int n_in,
                              void* d_out, int out_size, void* d_ws, size_t ws_size,
                              hipStream_t stream) {
    const float* x    = (const float*)d_in[0];
    const int*  ei    = (const int*)d_in[1];
    const int*  batch = (const int*)d_in[2];
    const float* ea   = (const float*)d_in[3];
    const float* Wemb = (const float*)d_in[4];
    const float* bemb = (const float*)d_in[5];
    const float* pW1  = (const float*)d_in[6];
    const float* pb1  = (const float*)d_in[7];
    const float* pW2  = (const float*)d_in[8];
    const float* pW3  = (const float*)d_in[9];
    const float* pb3  = (const float*)d_in[10];
    const float* Wf1  = (const float*)d_in[11];
    const float* bf1v = (const float*)d_in[12];
    const float* Wf2  = (const float*)d_in[13];
    const float* bf2v = (const float*)d_in[14];
    float* out = (float*)d_out;

    const int* src = ei;
    const int* dst = ei + N_EDGES;

    // ---- workspace layout ----
    const size_t NH = (size_t)N_NODES * H;
    char* p = (char*)d_ws;
    ushort* h       = (ushort*)p;            p += NH * 2;               // 12.8 MB
    ushort* m       = (ushort*)p;            p += NH * 2;               // 12.8 MB
    unsigned* epack = (unsigned*)p;          p += (size_t)N_EDGES * 4;  // 6.4 MB
    int*   histM    = (int*)p;               p += MHIST * 4;
    int*   incl     = (int*)p;               p += MHIST * 4;
    int*   partials = (int*)p;               p += 512 * 4;
    int*   bkt_ptr  = (int*)p;               p += (NBKT + 1) * 4;
    int*   row_ptr  = (int*)p;               p += (N_NODES + 1) * 4;
    float* degw     = (float*)p;             p += N_NODES * 4;
    float* Gbuf     = (float*)p;             p += 3 * 256 * 4;
    float* Cbuf     = (float*)p;             p += 3 * 64 * 4;
    // staging overlays m/h (dead until layer1; build completes first)
    unsigned* eb_se = (unsigned*)m;
    int*     eb_dst = (int*)h;

    // ---- CSR build: 4 dispatches (precomp fused into hist1, scans fused into scatter1) ----
    hist1_kernel<<<NBLK, 256, 0, stream>>>(dst, histM, Wemb, bemb, pW1, pb1, pW2, pW3, pb3,
                                           Gbuf, Cbuf);
    gscan1_kernel<<<MHIST / 512, 512, 0, stream>>>(histM, incl, partials);
    scatter1_kernel<<<NBLK, 256, 0, stream>>>(src, dst, ea, histM, incl, partials,
                                              eb_se, eb_dst, bkt_ptr);
    bucket_kernel<<<NBKT, 512, 0, stream>>>(bkt_ptr, eb_se, eb_dst, row_ptr, degw, epack);

    // ---- layer 1: fused x-gather + combine (1 dispatch) ----
    layer1_kernel<<<(N_NODES + 3) / 4, 256, 0, stream>>>(row_ptr, epack, x, degw,
                                                         Gbuf, Cbuf, h);

    // ---- layers 2,3: gather m from h, then MFMA lin in-place ----
    for (int l = 1; l < LAYERS; ++l) {
        gather_kernel<<<(N_NODES + 3) / 4, 256, 0, stream>>>(row_ptr, epack, h, m);
        linC_kernel<<<512, 256, 0, stream>>>(
            h, m, degw,
            pW1 + (size_t)l * H * H, pb1 + (size_t)l * H,
            pW2 + (size_t)l * H * H,
            pW3 + (size_t)l * H * H, pb3 + (size_t)l * H);
    }

    poolhead_kernel<<<N_GRAPHS, 256, 0, stream>>>(h, batch, Wf1, bf1v, Wf2, bf2v, out);
}